// Round 3
// baseline (1677.363 us; speedup 1.0000x reference)
//
#include <hip/hip_runtime.h>
#include <hip/hip_bf16.h>
#include <math.h>

typedef __attribute__((ext_vector_type(8))) short short8;
typedef __attribute__((ext_vector_type(4))) float f32x4;
typedef unsigned short ushort_t;
typedef unsigned int uint_t;

typedef __attribute__((address_space(1))) const void gvoid_t;
typedef __attribute__((address_space(3))) void lvoid_t;

#define VTILES 250
#define NBLK 256

static __device__ __forceinline__ ushort_t f2b(float f){
  __hip_bfloat16 h = __float2bfloat16(f);
  return *reinterpret_cast<ushort_t*>(&h);
}
static __device__ __forceinline__ float b2f(ushort_t u){
  __hip_bfloat16 h = *reinterpret_cast<__hip_bfloat16*>(&u);
  return __bfloat162float(h);
}
static __device__ __forceinline__ float sigmoidf_(float x){ return 1.0f/(1.0f+__expf(-x)); }

// sense-reversing grid barrier (device-scope atomics; bounded spin)
static __device__ __forceinline__ void grid_sync(uint_t* cnt, uint_t* gen){
  __syncthreads();
  if (threadIdx.x == 0){
    __threadfence();
    uint_t g = __hip_atomic_load(gen, __ATOMIC_RELAXED, __HIP_MEMORY_SCOPE_AGENT);
    uint_t a = __hip_atomic_fetch_add(cnt, 1u, __ATOMIC_ACQ_REL, __HIP_MEMORY_SCOPE_AGENT);
    if (a == NBLK - 1u){
      __hip_atomic_store(cnt, 0u, __ATOMIC_RELAXED, __HIP_MEMORY_SCOPE_AGENT);
      __hip_atomic_fetch_add(gen, 1u, __ATOMIC_RELEASE, __HIP_MEMORY_SCOPE_AGENT);
    } else {
      long spin = 0;
      while (__hip_atomic_load(gen, __ATOMIC_RELAXED, __HIP_MEMORY_SCOPE_AGENT) == g){
        __builtin_amdgcn_s_sleep(2);
        if (++spin > (1L<<28)) break;
      }
      __threadfence();
    }
  }
  __syncthreads();
}

// ---------- transpose + f32->bf16 convert: dst[c][dcoloff + r] = src[r][c] ----------
__global__ void k_transpose_cvt(const float* __restrict__ src, ushort_t* __restrict__ dst,
                                int C, int dstride, int dcoloff) {
  __shared__ ushort_t tile[64][72];
  int cb = blockIdx.x * 64, rb = blockIdx.y * 64;
  int tid = threadIdx.x;
  for (int it = 0; it < 4; ++it) {
    int e = tid + it*256;
    int row = e >> 4;
    int seg = e & 15;
    float4 v = *reinterpret_cast<const float4*>(&src[(size_t)(rb+row)*C + cb + seg*4]);
    tile[seg*4+0][row] = f2b(v.x);
    tile[seg*4+1][row] = f2b(v.y);
    tile[seg*4+2][row] = f2b(v.z);
    tile[seg*4+3][row] = f2b(v.w);
  }
  __syncthreads();
  for (int it = 0; it < 2; ++it) {
    int e = tid + it*256;
    int cl = e >> 3;
    int seg = e & 7;
    uint4 v = *reinterpret_cast<uint4*>(&tile[cl][seg*8]);
    *reinterpret_cast<uint4*>(&dst[(size_t)(cb+cl)*dstride + dcoloff + rb + seg*8]) = v;
  }
}

// ---------- embedding gather -> bf16 ----------
__global__ void k_embed(const int* __restrict__ captions, const float* __restrict__ W_embed,
                        ushort_t* __restrict__ xb) {
  int e = (blockIdx.x*256 + threadIdx.x) * 4;
  int nt = e >> 9;
  int n = nt >> 5, t = nt & 31;
  int col = e & 511;
  int tok = captions[n*33 + t];
  float4 v = *reinterpret_cast<const float4*>(&W_embed[(size_t)tok*512 + col]);
  ushort4 o; o.x=f2b(v.x); o.y=f2b(v.y); o.z=f2b(v.z); o.w=f2b(v.w);
  *reinterpret_cast<ushort4*>(&xb[e]) = o;
}

// ---------- A_flat = W_proj^T @ feat + b_proj ; h0 = mean_p ----------
__global__ void k_proj(const float* __restrict__ features, const float* __restrict__ W_proj,
                       const float* __restrict__ b_proj, float* __restrict__ A_flat,
                       float* __restrict__ hbuf) {
  __shared__ float fLds[16384];
  int kt = blockIdx.x, n = blockIdx.y;
  int tid = threadIdx.x;
  const float* fsrc = features + (size_t)n*16384;
  for (int it = 0; it < 16; ++it) {
    int e = tid + it*256;
    *reinterpret_cast<float4*>(&fLds[e*4]) = *reinterpret_cast<const float4*>(&fsrc[e*4]);
  }
  __syncthreads();
  int k = kt*256 + tid;
  float acc[16];
  #pragma unroll
  for (int p=0;p<16;++p) acc[p]=0.f;
  for (int d = 0; d < 1024; ++d) {
    float w = W_proj[(size_t)d*1024 + k];
    #pragma unroll
    for (int p=0;p<16;++p) acc[p] += fLds[d*16+p]*w;
  }
  float bp = b_proj[k];
  float s = 0.f;
  #pragma unroll
  for (int p=0;p<16;++p){ acc[p]+=bp; s+=acc[p]; }
  float* adst = A_flat + ((size_t)n*1024 + k)*16;
  #pragma unroll
  for (int p=0;p<16;p+=4)
    *reinterpret_cast<float4*>(&adst[p]) = make_float4(acc[p],acc[p+1],acc[p+2],acc[p+3]);
  hbuf[n*1024+k] = s * (1.f/16.f);
}

// ---------- P[n][j][p] = sum_k A_flat[n][k][p] * Wattn[k][j]  (bf16 out) ----------
// A-operand: A^T rows p (16), B-operand: WcatT rows j (attn cols 1536..2560)
__global__ void k_pgemm(const float* __restrict__ A_flat, const ushort_t* __restrict__ WcatT,
                        ushort_t* __restrict__ P) {
  __shared__ ushort_t aLds[16][72];
  __shared__ ushort_t wLds[64][72];
  int n = blockIdx.x, jt = blockIdx.y;
  int j0 = jt*64;
  int tid = threadIdx.x;
  int wave = tid>>6, lane = tid&63, lr = lane&15, lg = lane>>4;
  f32x4 acc = (f32x4){0.f,0.f,0.f,0.f};
  for (int kc = 0; kc < 1024; kc += 64){
    __syncthreads();
    {
      int k_l = tid >> 2, pg = (tid & 3)*4;
      float4 v = *reinterpret_cast<const float4*>(&A_flat[((size_t)n*1024 + kc + k_l)*16 + pg]);
      aLds[pg+0][k_l] = f2b(v.x);
      aLds[pg+1][k_l] = f2b(v.y);
      aLds[pg+2][k_l] = f2b(v.z);
      aLds[pg+3][k_l] = f2b(v.w);
    }
    for (int it = 0; it < 2; ++it){
      int e = tid + it*256;
      int row = e >> 3, seg = e & 7;
      *reinterpret_cast<uint4*>(&wLds[row][seg*8]) =
        *reinterpret_cast<const uint4*>(&WcatT[(size_t)(j0+row)*2560 + 1536 + kc + seg*8]);
    }
    __syncthreads();
    #pragma unroll
    for (int kk2 = 0; kk2 < 2; ++kk2){
      short8 af = *reinterpret_cast<short8*>(&aLds[lr][kk2*32 + lg*8]);
      short8 bf = *reinterpret_cast<short8*>(&wLds[wave*16 + lr][kk2*32 + lg*8]);
      acc = __builtin_amdgcn_mfma_f32_16x16x32_bf16(af, bf, acc, 0, 0, 0);
    }
  }
  // D: col=lane&15 -> j-local (wave*16+lr), row=lg*4+r -> p
  ushort4 st;
  st.x = f2b(acc[0]); st.y = f2b(acc[1]); st.z = f2b(acc[2]); st.w = f2b(acc[3]);
  *reinterpret_cast<ushort4*>(&P[((size_t)n*4096 + j0 + wave*16 + lr)*16 + lg*4]) = st;
}

// ---------- persistent LSTM: 32 steps, 2 grid syncs per step ----------
__global__ void __launch_bounds__(256, 1)
k_lstm(const ushort_t* __restrict__ WcatT, const ushort_t* __restrict__ xb,
       const float* __restrict__ A_flat, const float* __restrict__ hbuf,
       const float* __restrict__ bvec, const ushort_t* __restrict__ P,
       float* __restrict__ a_part, ushort_t* __restrict__ hbf,
       float* __restrict__ spart, ushort_t* __restrict__ hall,
       uint_t* barcnt, uint_t* bargen)
{
  __shared__ ushort_t Ws[6*64*64];        // 48KB: [chunk c][row j-local][64 cols swizzled]
  __shared__ char scratch[64*68*4];       // 17408B: zLds double-buffer (16KB) | Dt (17408B)
  __shared__ float sLds[64];
  __shared__ float wred[4][16];

  ushort_t* zLds = reinterpret_cast<ushort_t*>(scratch);
  float (*Dt)[68] = reinterpret_cast<float(*)[68]>(scratch);

  const int tid = threadIdx.x;
  const int wave = tid >> 6, lane = tid & 63;
  const int lr = lane & 15, lg = lane >> 4;
  const int b = blockIdx.x;
  const int nA = b >> 2, kblk = b & 3;
  const int kA = kblk*256 + tid;
  const int jt = b & 63, ks = b >> 6;
  const int j0 = jt * 64;
  const int srow = lane >> 3;
  const int sxor8 = ((lane & 7) ^ srow) * 8;

  // load Ws once: WcatT rows j0..j0+64, cols ks*384..+384 (x|h region only)
  #pragma unroll
  for (int c = 0; c < 6; ++c){
    #pragma unroll
    for (int u = 0; u < 2; ++u){
      int r0 = wave*16 + u*8;
      const ushort_t* src = &WcatT[(size_t)(j0 + r0 + srow)*2560 + ks*384 + c*64 + sxor8];
      __builtin_amdgcn_global_load_lds((gvoid_t*)src, (lvoid_t*)&Ws[(c*64 + r0)*64], 16, 0, 0);
    }
  }

  float c_state = 0.f, h_val = 0.f;

  for (int i = 0; i <= 32; ++i){
    // ======== PHASE A: h_i (+ spart_i) ========
    if (i == 0){
      h_val = hbuf[nA*1024 + kA];
      c_state = h_val;
    } else {
      if (tid < 64) sLds[tid] = spart[nA*64 + tid];
      __syncthreads();
      float sv[16]; float mx = -1e30f;
      #pragma unroll
      for (int p = 0; p < 16; ++p){
        sv[p] = (sLds[p] + sLds[16+p] + sLds[32+p] + sLds[48+p]) * (1.f/32.f);
        mx = fmaxf(mx, sv[p]);
      }
      float se = 0.f;
      #pragma unroll
      for (int p = 0; p < 16; ++p){ sv[p] = __expf(sv[p]-mx); se += sv[p]; }
      float inv = 1.f/se;
      float wv[16];
      #pragma unroll
      for (int p = 0; p < 16; ++p) wv[p] = sv[p]*inv;

      float av[4];
      #pragma unroll
      for (int g = 0; g < 4; ++g){
        int j = g*1024 + kA;
        float x = bvec[j];
        #pragma unroll
        for (int sp = 0; sp < 4; ++sp) x += a_part[((size_t)sp*64 + nA)*4096 + j];
        const ushort_t* pp = &P[((size_t)nA*4096 + j)*16];
        short8 p0 = *reinterpret_cast<const short8*>(pp);
        short8 p1 = *reinterpret_cast<const short8*>(pp + 8);
        #pragma unroll
        for (int p = 0; p < 8; ++p) x += wv[p]   * b2f((ushort_t)p0[p]);
        #pragma unroll
        for (int p = 0; p < 8; ++p) x += wv[8+p] * b2f((ushort_t)p1[p]);
        av[g] = x;
      }
      float ig = sigmoidf_(av[0]), fg = sigmoidf_(av[1]);
      float og = sigmoidf_(av[2]), gg = tanhf(av[3]);
      c_state = fg*c_state + ig*gg;
      h_val = og*tanhf(c_state);
      hall[((size_t)nA*32 + (i-1))*1024 + kA] = f2b(h_val);
      __syncthreads();
    }
    if (i == 32) break;

    hbf[nA*1024 + kA] = f2b(h_val);
    {
      float sacc[16];
      const float* An = &A_flat[((size_t)nA*1024 + kA)*16];
      #pragma unroll
      for (int p = 0; p < 16; ++p) sacc[p] = h_val * An[p];
      #pragma unroll
      for (int d = 1; d < 64; d <<= 1)
        #pragma unroll
        for (int p = 0; p < 16; ++p) sacc[p] += __shfl_xor(sacc[p], d, 64);
      if (lane == 0)
        #pragma unroll
        for (int p = 0; p < 16; ++p) wred[wave][p] = sacc[p];
      __syncthreads();
      if (tid < 16)
        spart[(nA*4 + kblk)*16 + tid] = wred[0][tid]+wred[1][tid]+wred[2][tid]+wred[3][tid];
    }

    grid_sync(barcnt, bargen);   // h_i, spart_i visible

    // ======== PHASE C: a_part[ks] += [x_i|h_i] @ Wcat slice ========
    f32x4 acc[4];
    #pragma unroll
    for (int nf = 0; nf < 4; ++nf) acc[nf] = (f32x4){0.f,0.f,0.f,0.f};

    auto stage = [&](int buf, int c){
      int gc0 = ks*384 + c*64;
      #pragma unroll
      for (int u = 0; u < 2; ++u){
        int r0 = wave*16 + u*8;
        int n = r0 + srow;
        const ushort_t* src;
        if (gc0 < 512) src = &xb[((size_t)n*32 + i)*512 + gc0 + sxor8];
        else           src = &hbf[(size_t)n*1024 + (gc0 - 512) + sxor8];
        __builtin_amdgcn_global_load_lds((gvoid_t*)src, (lvoid_t*)&zLds[buf*4096 + r0*64], 16, 0, 0);
      }
    };

    int cur = 0;
    stage(0, 0);
    for (int c = 0; c < 6; ++c){
      __syncthreads();                       // drain gloads of buf cur; prior reads done
      if (c + 1 < 6) stage(cur ^ 1, c + 1);
      #pragma unroll
      for (int kk2 = 0; kk2 < 2; ++kk2){
        int swz = (((kk2*4 + lg) ^ (lr & 7)) * 8);
        short8 af = *reinterpret_cast<short8*>(&Ws[(c*64 + wave*16 + lr)*64 + swz]);
        #pragma unroll
        for (int nf = 0; nf < 4; ++nf){
          short8 bf = *reinterpret_cast<short8*>(&zLds[cur*4096 + (nf*16 + lr)*64 + swz]);
          acc[nf] = __builtin_amdgcn_mfma_f32_16x16x32_bf16(af, bf, acc[nf], 0, 0, 0);
        }
      }
      cur ^= 1;
    }
    __syncthreads();                         // zLds reads done -> scratch becomes Dt
    #pragma unroll
    for (int nf = 0; nf < 4; ++nf)
      #pragma unroll
      for (int r = 0; r < 4; ++r)
        Dt[nf*16+lr][wave*16 + lg*4 + r] = acc[nf][r];
    __syncthreads();
    #pragma unroll
    for (int it = 0; it < 4; ++it){
      int e = it*256 + tid;
      int nrow = e >> 4, seg = e & 15;
      float4 v = *reinterpret_cast<float4*>(&Dt[nrow][seg*4]);
      *reinterpret_cast<float4*>(&a_part[((size_t)ks*64 + nrow)*4096 + j0 + seg*4]) = v;
    }

    grid_sync(barcnt, bargen);   // a_part visible
  }
}

// ---------- scores tile + fused partial logsumexp over 128-v tile ----------
__global__ void __launch_bounds__(256, 4)
k_score(const ushort_t* __restrict__ WoutT, const ushort_t* __restrict__ hall,
        const float* __restrict__ b_out,
        float* __restrict__ pmax, float* __restrict__ psum) {
  __shared__ ushort_t As[128*64];
  __shared__ ushort_t Bs[128*64];
  __shared__ float bLds[128];
  __shared__ float pmLds[4][128];
  __shared__ float psLds[4][128];
  int bid = blockIdx.x;
  int wg = (bid & 7) * 500 + (bid >> 3);
  int vb = wg >> 4, rb = wg & 15;
  int v0 = vb * 128, r0 = rb * 128;
  int tid = threadIdx.x;
  int wave = tid >> 6, lane = tid & 63, lr = lane & 15, lg = lane >> 4;
  if (tid < 128) bLds[tid] = b_out[v0 + tid];

  int srow = lane >> 3;
  int sxor = ((lane & 7) ^ srow) << 3;

  f32x4 acc[2][8];
  #pragma unroll
  for (int a=0;a<2;++a)
    #pragma unroll
    for (int q=0;q<8;++q) acc[a][q]=(f32x4){0.f,0.f,0.f,0.f};

  for (int kc = 0; kc < 1024; kc += 64) {
    __syncthreads();
    #pragma unroll
    for (int i = 0; i < 4; ++i) {
      int rowg = (wave*4 + i) * 8;
      const ushort_t* gsA = &WoutT[(size_t)(v0 + rowg + srow)*1024 + kc + sxor];
      const ushort_t* gsB = &hall [(size_t)(r0 + rowg + srow)*1024 + kc + sxor];
      __builtin_amdgcn_global_load_lds((gvoid_t*)gsA, (lvoid_t*)&As[rowg*64], 16, 0, 0);
      __builtin_amdgcn_global_load_lds((gvoid_t*)gsB, (lvoid_t*)&Bs[rowg*64], 16, 0, 0);
    }
    __syncthreads();
    #pragma unroll
    for (int kk = 0; kk < 2; ++kk) {
      int swz = ((kk*4 + lg) ^ (lr & 7)) << 3;
      int rowA = wave*32 + lr;
      short8 af0 = *reinterpret_cast<short8*>(&As[rowA*64 + swz]);
      short8 af1 = *reinterpret_cast<short8*>(&As[(rowA+16)*64 + swz]);
      #pragma unroll
      for (int nr = 0; nr < 8; ++nr) {
        short8 bf = *reinterpret_cast<short8*>(&Bs[(nr*16+lr)*64 + swz]);
        acc[0][nr] = __builtin_amdgcn_mfma_f32_16x16x32_bf16(af0, bf, acc[0][nr], 0,0,0);
        acc[1][nr] = __builtin_amdgcn_mfma_f32_16x16x32_bf16(af1, bf, acc[1][nr], 0,0,0);
      }
    }
  }
  #pragma unroll
  for (int nr=0;nr<8;++nr){
    float m = -1e30f;
    float xv[8];
    #pragma unroll
    for (int mv=0;mv<2;++mv)
      #pragma unroll
      for (int r=0;r<4;++r){
        float x = acc[mv][nr][r] + bLds[wave*32 + mv*16 + lg*4 + r];
        xv[mv*4+r]=x; m = fmaxf(m,x);
      }
    float s=0.f;
    #pragma unroll
    for (int i=0;i<8;++i) s += __expf(xv[i]-m);
    #pragma unroll
    for (int d=16; d<=32; d<<=1){
      float om = __shfl_xor(m, d, 64);
      float os = __shfl_xor(s, d, 64);
      float nm = fmaxf(m, om);
      s = s*__expf(m-nm) + os*__expf(om-nm);
      m = nm;
    }
    if (lg == 0){
      pmLds[wave][nr*16+lr] = m;
      psLds[wave][nr*16+lr] = s;
    }
  }
  __syncthreads();
  if (tid < 128){
    float m=-1e30f;
    #pragma unroll
    for (int w=0;w<4;++w) m = fmaxf(m, pmLds[w][tid]);
    float s=0.f;
    #pragma unroll
    for (int w=0;w<4;++w) s += psLds[w][tid]*__expf(pmLds[w][tid]-m);
    pmax[(size_t)(r0+tid)*VTILES + vb] = m;
    psum[(size_t)(r0+tid)*VTILES + vb] = s;
  }
}

// ---------- target scores ----------
__global__ void k_tgt(const ushort_t* __restrict__ hall, const ushort_t* __restrict__ WoutT,
                      const float* __restrict__ b_out, const int* __restrict__ captions,
                      float* __restrict__ stgt) {
  int tid = threadIdx.x;
  int wave = tid>>6, lane = tid&63;
  int r = blockIdx.x*4 + wave;
  int n = r>>5, t = r&31;
  int y = captions[n*33 + t + 1];
  const ushort_t* hrow = hall + (size_t)r*1024;
  const ushort_t* wrow = WoutT + (size_t)y*1024;
  float dot = 0.f;
  #pragma unroll
  for (int i=0;i<2;++i){
    int off = lane*8 + i*512;
    short8 hv = *reinterpret_cast<const short8*>(&hrow[off]);
    short8 wv = *reinterpret_cast<const short8*>(&wrow[off]);
    #pragma unroll
    for (int e2=0;e2<8;++e2) dot += b2f((ushort_t)hv[e2])*b2f((ushort_t)wv[e2]);
  }
  #pragma unroll
  for (int d=32; d>=1; d>>=1) dot += __shfl_xor(dot, d, 64);
  if (lane==0) stgt[r] = dot + b_out[y];
}

// ---------- combine partials -> per-row masked nll ----------
__global__ void k_reduce(const float* __restrict__ pmax, const float* __restrict__ psum,
                         const float* __restrict__ stgt, const int* __restrict__ captions,
                         float* __restrict__ row_loss) {
  int tid = threadIdx.x;
  int wave = tid>>6, lane = tid&63;
  int r = blockIdx.x*4 + wave;
  float m = -1e30f, s = 0.f;
  for (int j = lane; j < VTILES; j += 64){
    float mj = pmax[(size_t)r*VTILES + j];
    float sj = psum[(size_t)r*VTILES + j];
    float nm = fmaxf(m, mj);
    s = s*__expf(m-nm) + sj*__expf(mj-nm);
    m = nm;
  }
  #pragma unroll
  for (int d=32; d>=1; d>>=1){
    float om = __shfl_xor(m, d, 64);
    float os = __shfl_xor(s, d, 64);
    float nm = fmaxf(m, om);
    s = s*__expf(m-nm) + os*__expf(om-nm);
    m = nm;
  }
  if (lane==0){
    int n = r>>5, t = r&31;
    int y = captions[n*33 + t + 1];
    float lse = m + __logf(s);
    row_loss[r] = (y != 0) ? (lse - stgt[r]) : 0.f;
  }
}

// ---------- final deterministic sum ----------
__global__ void k_final(const float* __restrict__ row_loss, float* __restrict__ out) {
  __shared__ float red[256];
  int tid = threadIdx.x;
  float s = 0.f;
  #pragma unroll
  for (int i=0;i<8;++i) s += row_loss[tid + i*256];
  red[tid] = s;
  __syncthreads();
  for (int off=128; off>=1; off>>=1){
    if (tid<off) red[tid] += red[tid+off];
    __syncthreads();
  }
  if (tid==0) out[0] = red[0] * (1.f/64.f);
}

extern "C" void kernel_launch(void* const* d_in, const int* in_sizes, int n_in,
                              void* d_out, int out_size, void* d_ws, size_t ws_size,
                              hipStream_t stream) {
  const float* features = (const float*)d_in[0];
  const int*   captions = (const int*)d_in[1];
  const float* W_embed  = (const float*)d_in[2];
  const float* Wx       = (const float*)d_in[3];
  const float* Wh       = (const float*)d_in[4];
  const float* Wattn    = (const float*)d_in[5];
  const float* b        = (const float*)d_in[6];
  const float* W_proj   = (const float*)d_in[7];
  const float* b_proj   = (const float*)d_in[8];
  const float* W_out    = (const float*)d_in[9];
  const float* b_out    = (const float*)d_in[10];
  float* out = (float*)d_out;

  char* wsp = (char*)d_ws;
  size_t off = 0;
  auto alloc = [&](size_t bytes)->char*{
    char* p = wsp + off; off += (bytes + 255) & ~(size_t)255; return p;
  };
  ushort_t* WcatT = (ushort_t*)alloc((size_t)4096*2560*2);
  ushort_t* WoutT = (ushort_t*)alloc((size_t)32000*1024*2);
  float* A_flat   = (float*)alloc((size_t)64*1024*16*4);
  ushort_t* xb    = (ushort_t*)alloc((size_t)64*32*512*2);
  float* hbuf     = (float*)alloc((size_t)64*1024*4);
  ushort_t* Pbuf  = (ushort_t*)alloc((size_t)64*4096*16*2);
  float* a_part   = (float*)alloc((size_t)4*64*4096*4);
  ushort_t* hbf   = (ushort_t*)alloc((size_t)64*1024*2);
  float* spart    = (float*)alloc((size_t)64*4*16*4);
  ushort_t* hall  = (ushort_t*)alloc((size_t)2048*1024*2);
  float* pmax     = (float*)alloc((size_t)2048*250*4);
  float* psum     = (float*)alloc((size_t)2048*250*4);
  float* stgt     = (float*)alloc((size_t)2048*4);
  float* row_loss = (float*)alloc((size_t)2048*4);
  uint_t* barr    = (uint_t*)alloc(256);   // [0]=cnt, [64]=gen (separate lines)

  hipLaunchKernelGGL(k_transpose_cvt, dim3(64, 8),   dim3(256), 0, stream, Wx,    WcatT, 4096, 2560, 0);
  hipLaunchKernelGGL(k_transpose_cvt, dim3(64, 16),  dim3(256), 0, stream, Wh,    WcatT, 4096, 2560, 512);
  hipLaunchKernelGGL(k_transpose_cvt, dim3(64, 16),  dim3(256), 0, stream, Wattn, WcatT, 4096, 2560, 1536);
  hipLaunchKernelGGL(k_transpose_cvt, dim3(500, 16), dim3(256), 0, stream, W_out, WoutT, 32000, 1024, 0);
  hipLaunchKernelGGL(k_embed, dim3(1024), dim3(256), 0, stream, captions, W_embed, xb);
  hipLaunchKernelGGL(k_proj, dim3(4, 64), dim3(256), 0, stream, features, W_proj, b_proj, A_flat, hbuf);
  hipLaunchKernelGGL(k_pgemm, dim3(64, 64), dim3(256), 0, stream, A_flat, WcatT, Pbuf);

  hipMemsetAsync(barr, 0, 256, stream);
  hipLaunchKernelGGL(k_lstm, dim3(NBLK), dim3(256), 0, stream,
                     WcatT, xb, A_flat, hbuf, b, Pbuf,
                     a_part, hbf, spart, hall, &barr[0], &barr[64]);

  hipLaunchKernelGGL(k_score, dim3(4000), dim3(256), 0, stream, WoutT, hall, b_out, pmax, psum);
  hipLaunchKernelGGL(k_tgt, dim3(512), dim3(256), 0, stream, hall, WoutT, b_out, captions, stgt);
  hipLaunchKernelGGL(k_reduce, dim3(512), dim3(256), 0, stream, pmax, psum, stgt, captions, row_loss);
  hipLaunchKernelGGL(k_final, dim3(1), dim3(256), 0, stream, row_loss, out);
}

// Round 4
// 876.064 us; speedup vs baseline: 1.9147x; 1.9147x over previous
//
#include <hip/hip_runtime.h>
#include <hip/hip_bf16.h>
#include <math.h>

typedef __attribute__((ext_vector_type(8))) short short8;
typedef __attribute__((ext_vector_type(4))) float f32x4;
typedef unsigned short ushort_t;
typedef unsigned int uint_t;

typedef __attribute__((address_space(1))) const void gvoid_t;
typedef __attribute__((address_space(3))) void lvoid_t;

#define VTILES 250

static __device__ __forceinline__ ushort_t f2b(float f){
  __hip_bfloat16 h = __float2bfloat16(f);
  return *reinterpret_cast<ushort_t*>(&h);
}
static __device__ __forceinline__ float b2f(ushort_t u){
  __hip_bfloat16 h = *reinterpret_cast<__hip_bfloat16*>(&u);
  return __bfloat162float(h);
}
static __device__ __forceinline__ float sigmoidf_(float x){ return 1.0f/(1.0f+__expf(-x)); }

// ---------- transpose + f32->bf16 convert: dst[c][dcoloff + r] = src[r][c] ----------
__global__ void k_transpose_cvt(const float* __restrict__ src, ushort_t* __restrict__ dst,
                                int C, int dstride, int dcoloff) {
  __shared__ ushort_t tile[64][72];
  int cb = blockIdx.x * 64, rb = blockIdx.y * 64;
  int tid = threadIdx.x;
  for (int it = 0; it < 4; ++it) {
    int e = tid + it*256;
    int row = e >> 4;
    int seg = e & 15;
    float4 v = *reinterpret_cast<const float4*>(&src[(size_t)(rb+row)*C + cb + seg*4]);
    tile[seg*4+0][row] = f2b(v.x);
    tile[seg*4+1][row] = f2b(v.y);
    tile[seg*4+2][row] = f2b(v.z);
    tile[seg*4+3][row] = f2b(v.w);
  }
  __syncthreads();
  for (int it = 0; it < 2; ++it) {
    int e = tid + it*256;
    int cl = e >> 3;
    int seg = e & 7;
    uint4 v = *reinterpret_cast<uint4*>(&tile[cl][seg*8]);
    *reinterpret_cast<uint4*>(&dst[(size_t)(cb+cl)*dstride + dcoloff + rb + seg*8]) = v;
  }
}

// ---------- embedding gather -> bf16 ----------
__global__ void k_embed(const int* __restrict__ captions, const float* __restrict__ W_embed,
                        ushort_t* __restrict__ xb) {
  int e = (blockIdx.x*256 + threadIdx.x) * 4;
  int nt = e >> 9;
  int n = nt >> 5, t = nt & 31;
  int col = e & 511;
  int tok = captions[n*33 + t];
  float4 v = *reinterpret_cast<const float4*>(&W_embed[(size_t)tok*512 + col]);
  ushort4 o; o.x=f2b(v.x); o.y=f2b(v.y); o.z=f2b(v.z); o.w=f2b(v.w);
  *reinterpret_cast<ushort4*>(&xb[e]) = o;
}

// ---------- A_flat = W_proj^T @ feat + b_proj ; h0 = mean_p ----------
__global__ void k_proj(const float* __restrict__ features, const float* __restrict__ W_proj,
                       const float* __restrict__ b_proj, float* __restrict__ A_flat,
                       float* __restrict__ hbuf) {
  __shared__ float fLds[16384];
  int kt = blockIdx.x, n = blockIdx.y;
  int tid = threadIdx.x;
  const float* fsrc = features + (size_t)n*16384;
  for (int it = 0; it < 16; ++it) {
    int e = tid + it*256;
    *reinterpret_cast<float4*>(&fLds[e*4]) = *reinterpret_cast<const float4*>(&fsrc[e*4]);
  }
  __syncthreads();
  int k = kt*256 + tid;
  float acc[16];
  #pragma unroll
  for (int p=0;p<16;++p) acc[p]=0.f;
  for (int d = 0; d < 1024; ++d) {
    float w = W_proj[(size_t)d*1024 + k];
    #pragma unroll
    for (int p=0;p<16;++p) acc[p] += fLds[d*16+p]*w;
  }
  float bp = b_proj[k];
  float s = 0.f;
  #pragma unroll
  for (int p=0;p<16;++p){ acc[p]+=bp; s+=acc[p]; }
  float* adst = A_flat + ((size_t)n*1024 + k)*16;
  #pragma unroll
  for (int p=0;p<16;p+=4)
    *reinterpret_cast<float4*>(&adst[p]) = make_float4(acc[p],acc[p+1],acc[p+2],acc[p+3]);
  hbuf[n*1024+k] = s * (1.f/16.f);
}

// ---------- P[n][j][p] = sum_k A_flat[n][k][p] * Wattn[k][j]  (bf16 out) ----------
__global__ void k_pgemm(const float* __restrict__ A_flat, const ushort_t* __restrict__ WcatT,
                        ushort_t* __restrict__ P) {
  __shared__ ushort_t aLds[16][72];
  __shared__ ushort_t wLds[64][72];
  int n = blockIdx.x, jt = blockIdx.y;
  int j0 = jt*64;
  int tid = threadIdx.x;
  int wave = tid>>6, lane = tid&63, lr = lane&15, lg = lane>>4;
  f32x4 acc = (f32x4){0.f,0.f,0.f,0.f};
  for (int kc = 0; kc < 1024; kc += 64){
    __syncthreads();
    {
      int k_l = tid >> 2, pg = (tid & 3)*4;
      float4 v = *reinterpret_cast<const float4*>(&A_flat[((size_t)n*1024 + kc + k_l)*16 + pg]);
      aLds[pg+0][k_l] = f2b(v.x);
      aLds[pg+1][k_l] = f2b(v.y);
      aLds[pg+2][k_l] = f2b(v.z);
      aLds[pg+3][k_l] = f2b(v.w);
    }
    for (int it = 0; it < 2; ++it){
      int e = tid + it*256;
      int row = e >> 3, seg = e & 7;
      *reinterpret_cast<uint4*>(&wLds[row][seg*8]) =
        *reinterpret_cast<const uint4*>(&WcatT[(size_t)(j0+row)*2560 + 1536 + kc + seg*8]);
    }
    __syncthreads();
    #pragma unroll
    for (int kk2 = 0; kk2 < 2; ++kk2){
      short8 af = *reinterpret_cast<short8*>(&aLds[lr][kk2*32 + lg*8]);
      short8 bf = *reinterpret_cast<short8*>(&wLds[wave*16 + lr][kk2*32 + lg*8]);
      acc = __builtin_amdgcn_mfma_f32_16x16x32_bf16(af, bf, acc, 0, 0, 0);
    }
  }
  ushort4 st;
  st.x = f2b(acc[0]); st.y = f2b(acc[1]); st.z = f2b(acc[2]); st.w = f2b(acc[3]);
  *reinterpret_cast<ushort4*>(&P[((size_t)n*4096 + j0 + wave*16 + lr)*16 + lg*4]) = st;
}

// ---------- xpre[nt][j] = sum_k xb[nt][k] * Wx[k][j]  (bf16 out, f32 accum) ----------
__global__ void k_xmm(const ushort_t* __restrict__ WcatT, const ushort_t* __restrict__ xb,
                      ushort_t* __restrict__ xpre) {
  __shared__ ushort_t As[64*64];
  __shared__ ushort_t Bs[64*64];
  __shared__ float Dt[64][68];
  int jt = blockIdx.x, mt = blockIdx.y;
  int j0 = jt*64, m0 = mt*64;
  int tid = threadIdx.x;
  int wave = tid>>6, lane = tid&63, lr = lane&15, lg = lane>>4;
  int srow = lane>>3, sxor8 = ((lane&7)^srow)*8;
  f32x4 acc[4];
  #pragma unroll
  for (int nf=0;nf<4;++nf) acc[nf] = (f32x4){0.f,0.f,0.f,0.f};
  for (int kc = 0; kc < 512; kc += 64){
    __syncthreads();
    #pragma unroll
    for (int u = 0; u < 2; ++u){
      int r0 = wave*16 + u*8;
      const ushort_t* srcA = &WcatT[(size_t)(j0 + r0 + srow)*2560 + kc + sxor8];
      const ushort_t* srcB = &xb[(size_t)(m0 + r0 + srow)*512 + kc + sxor8];
      __builtin_amdgcn_global_load_lds((gvoid_t*)srcA, (lvoid_t*)&As[r0*64], 16, 0, 0);
      __builtin_amdgcn_global_load_lds((gvoid_t*)srcB, (lvoid_t*)&Bs[r0*64], 16, 0, 0);
    }
    __syncthreads();
    #pragma unroll
    for (int kk = 0; kk < 2; ++kk){
      int swz = (((kk*4 + lg) ^ (lr & 7)) * 8);
      short8 af = *reinterpret_cast<short8*>(&As[(wave*16 + lr)*64 + swz]);
      #pragma unroll
      for (int nf = 0; nf < 4; ++nf){
        short8 bf = *reinterpret_cast<short8*>(&Bs[(nf*16 + lr)*64 + swz]);
        acc[nf] = __builtin_amdgcn_mfma_f32_16x16x32_bf16(af, bf, acc[nf], 0, 0, 0);
      }
    }
  }
  __syncthreads();
  #pragma unroll
  for (int nf=0; nf<4; ++nf)
    #pragma unroll
    for (int r=0;r<4;++r)
      Dt[nf*16+lr][wave*16 + lg*4 + r] = acc[nf][r];
  __syncthreads();
  #pragma unroll
  for (int it=0; it<4; ++it){
    int e = tid + it*256;
    int nrow = e >> 4, seg = e & 15;
    float4 v = *reinterpret_cast<float4*>(&Dt[nrow][seg*4]);
    ushort4 o; o.x=f2b(v.x); o.y=f2b(v.y); o.z=f2b(v.z); o.w=f2b(v.w);
    *reinterpret_cast<ushort4*>(&xpre[(size_t)(m0+nrow)*4096 + j0 + seg*4]) = o;
  }
}

// ---------- per-step gates + c/h update + full-row softmax -> wv ----------
__global__ void k_gate(int i, const ushort_t* __restrict__ xpre, const float* __restrict__ a_part,
                       const float* __restrict__ bvec, const ushort_t* __restrict__ P,
                       const float* __restrict__ A_flat, const float* __restrict__ hbuf,
                       float* __restrict__ cbuf, float* __restrict__ wvbuf,
                       ushort_t* __restrict__ hbf, ushort_t* __restrict__ hall) {
  __shared__ float wvLds[16];
  __shared__ float wred[4][16];
  int n = blockIdx.x, tid = threadIdx.x;
  int wave = tid>>6, lane = tid&63;
  float h[4];
  if (i == 0){
    #pragma unroll
    for (int u=0;u<4;++u){
      int k = tid + 256*u;
      float hv = hbuf[n*1024+k];
      h[u] = hv;
      cbuf[n*1024+k] = hv;
      hbf[n*1024+k] = f2b(hv);
    }
  } else {
    if (tid < 16) wvLds[tid] = wvbuf[n*16+tid];
    __syncthreads();
    float wv[16];
    #pragma unroll
    for (int p=0;p<16;++p) wv[p] = wvLds[p];
    #pragma unroll
    for (int u=0;u<4;++u){
      int k = tid + 256*u;
      float av[4];
      #pragma unroll
      for (int g=0;g<4;++g){
        int j = g*1024 + k;
        float x = bvec[j] + b2f(xpre[(size_t)(n*32 + (i-1))*4096 + j]);
        #pragma unroll
        for (int ks=0;ks<4;++ks) x += a_part[((size_t)ks*64 + n)*4096 + j];
        const ushort_t* pp = &P[((size_t)n*4096 + j)*16];
        short8 p0 = *reinterpret_cast<const short8*>(pp);
        short8 p1 = *reinterpret_cast<const short8*>(pp+8);
        #pragma unroll
        for (int p=0;p<8;++p) x += wv[p]*b2f((ushort_t)p0[p]);
        #pragma unroll
        for (int p=0;p<8;++p) x += wv[8+p]*b2f((ushort_t)p1[p]);
        av[g]=x;
      }
      float ig=sigmoidf_(av[0]), fg=sigmoidf_(av[1]), og=sigmoidf_(av[2]), gg=tanhf(av[3]);
      float c = fg*cbuf[n*1024+k] + ig*gg;
      float hv = og*tanhf(c);
      cbuf[n*1024+k] = c;
      h[u] = hv;
      hall[((size_t)n*32 + (i-1))*1024 + k] = f2b(hv);
      if (i < 32) hbf[n*1024+k] = f2b(hv);
    }
  }
  if (i == 32) return;
  // softmax over p of (h . A_flat[n,:,p]) / 32
  float sacc[16];
  #pragma unroll
  for (int p=0;p<16;++p) sacc[p]=0.f;
  #pragma unroll
  for (int u=0;u<4;++u){
    int k = tid + 256*u;
    const float* An = &A_flat[((size_t)n*1024 + k)*16];
    float hv = h[u];
    #pragma unroll
    for (int p=0;p<16;p+=4){
      float4 a4 = *reinterpret_cast<const float4*>(&An[p]);
      sacc[p] += hv*a4.x; sacc[p+1] += hv*a4.y; sacc[p+2] += hv*a4.z; sacc[p+3] += hv*a4.w;
    }
  }
  #pragma unroll
  for (int d=1; d<64; d<<=1)
    #pragma unroll
    for (int p=0;p<16;++p) sacc[p] += __shfl_xor(sacc[p], d, 64);
  if (lane == 0)
    #pragma unroll
    for (int p=0;p<16;++p) wred[wave][p] = sacc[p];
  __syncthreads();
  if (tid < 16){
    float sv = (wred[0][tid]+wred[1][tid]+wred[2][tid]+wred[3][tid]) * (1.f/32.f);
    float m = sv;
    #pragma unroll
    for (int d=1; d<16; d<<=1) m = fmaxf(m, __shfl_xor(m, d, 64));
    float e = __expf(sv - m);
    float s = e;
    #pragma unroll
    for (int d=1; d<16; d<<=1) s += __shfl_xor(s, d, 64);
    wvbuf[n*16+tid] = e / s;
  }
}

// ---------- a_part[ks] = h @ Wh (K-chunk ks of 256) ----------
__global__ void k_mm(const ushort_t* __restrict__ WcatT, const ushort_t* __restrict__ hbf,
                     float* __restrict__ a_part) {
  __shared__ ushort_t As[64*64];
  __shared__ ushort_t Bs[64*64];
  __shared__ float Dt[64][68];
  int jt = blockIdx.x, ks = blockIdx.y;
  int j0 = jt*64;
  int tid = threadIdx.x;
  int wave = tid>>6, lane = tid&63, lr = lane&15, lg = lane>>4;
  int srow = lane>>3, sxor8 = ((lane&7)^srow)*8;
  f32x4 acc[4];
  #pragma unroll
  for (int nf=0;nf<4;++nf) acc[nf] = (f32x4){0.f,0.f,0.f,0.f};
  for (int kc = 0; kc < 256; kc += 64){
    __syncthreads();
    #pragma unroll
    for (int u = 0; u < 2; ++u){
      int r0 = wave*16 + u*8;
      const ushort_t* srcA = &WcatT[(size_t)(j0 + r0 + srow)*2560 + 512 + ks*256 + kc + sxor8];
      const ushort_t* srcB = &hbf[(size_t)(r0 + srow)*1024 + ks*256 + kc + sxor8];
      __builtin_amdgcn_global_load_lds((gvoid_t*)srcA, (lvoid_t*)&As[r0*64], 16, 0, 0);
      __builtin_amdgcn_global_load_lds((gvoid_t*)srcB, (lvoid_t*)&Bs[r0*64], 16, 0, 0);
    }
    __syncthreads();
    #pragma unroll
    for (int kk = 0; kk < 2; ++kk){
      int swz = (((kk*4 + lg) ^ (lr & 7)) * 8);
      short8 af = *reinterpret_cast<short8*>(&As[(wave*16 + lr)*64 + swz]);
      #pragma unroll
      for (int nf = 0; nf < 4; ++nf){
        short8 bf = *reinterpret_cast<short8*>(&Bs[(nf*16 + lr)*64 + swz]);
        acc[nf] = __builtin_amdgcn_mfma_f32_16x16x32_bf16(af, bf, acc[nf], 0, 0, 0);
      }
    }
  }
  __syncthreads();
  #pragma unroll
  for (int nf=0; nf<4; ++nf)
    #pragma unroll
    for (int r=0;r<4;++r)
      Dt[nf*16+lr][wave*16 + lg*4 + r] = acc[nf][r];
  __syncthreads();
  #pragma unroll
  for (int it=0; it<4; ++it){
    int e = tid + it*256;
    int nrow = e >> 4, seg = e & 15;
    float4 v = *reinterpret_cast<float4*>(&Dt[nrow][seg*4]);
    *reinterpret_cast<float4*>(&a_part[((size_t)ks*64 + nrow)*4096 + j0 + seg*4]) = v;
  }
}

// ---------- scores tile + fused partial logsumexp over 128-v tile ----------
__global__ void __launch_bounds__(256, 4)
k_score(const ushort_t* __restrict__ WoutT, const ushort_t* __restrict__ hall,
        const float* __restrict__ b_out,
        float* __restrict__ pmax, float* __restrict__ psum) {
  __shared__ ushort_t As[128*64];
  __shared__ ushort_t Bs[128*64];
  __shared__ float bLds[128];
  __shared__ float pmLds[4][128];
  __shared__ float psLds[4][128];
  int bid = blockIdx.x;
  int wg = (bid & 7) * 500 + (bid >> 3);
  int vb = wg >> 4, rb = wg & 15;
  int v0 = vb * 128, r0 = rb * 128;
  int tid = threadIdx.x;
  int wave = tid >> 6, lane = tid & 63, lr = lane & 15, lg = lane >> 4;
  if (tid < 128) bLds[tid] = b_out[v0 + tid];

  int srow = lane >> 3;
  int sxor = ((lane & 7) ^ srow) << 3;

  f32x4 acc[2][8];
  #pragma unroll
  for (int a=0;a<2;++a)
    #pragma unroll
    for (int q=0;q<8;++q) acc[a][q]=(f32x4){0.f,0.f,0.f,0.f};

  for (int kc = 0; kc < 1024; kc += 64) {
    __syncthreads();
    #pragma unroll
    for (int i = 0; i < 4; ++i) {
      int rowg = (wave*4 + i) * 8;
      const ushort_t* gsA = &WoutT[(size_t)(v0 + rowg + srow)*1024 + kc + sxor];
      const ushort_t* gsB = &hall [(size_t)(r0 + rowg + srow)*1024 + kc + sxor];
      __builtin_amdgcn_global_load_lds((gvoid_t*)gsA, (lvoid_t*)&As[rowg*64], 16, 0, 0);
      __builtin_amdgcn_global_load_lds((gvoid_t*)gsB, (lvoid_t*)&Bs[rowg*64], 16, 0, 0);
    }
    __syncthreads();
    #pragma unroll
    for (int kk = 0; kk < 2; ++kk) {
      int swz = ((kk*4 + lg) ^ (lr & 7)) << 3;
      int rowA = wave*32 + lr;
      short8 af0 = *reinterpret_cast<short8*>(&As[rowA*64 + swz]);
      short8 af1 = *reinterpret_cast<short8*>(&As[(rowA+16)*64 + swz]);
      #pragma unroll
      for (int nr = 0; nr < 8; ++nr) {
        short8 bf = *reinterpret_cast<short8*>(&Bs[(nr*16+lr)*64 + swz]);
        acc[0][nr] = __builtin_amdgcn_mfma_f32_16x16x32_bf16(af0, bf, acc[0][nr], 0,0,0);
        acc[1][nr] = __builtin_amdgcn_mfma_f32_16x16x32_bf16(af1, bf, acc[1][nr], 0,0,0);
      }
    }
  }
  #pragma unroll
  for (int nr=0;nr<8;++nr){
    float m = -1e30f;
    float xv[8];
    #pragma unroll
    for (int mv=0;mv<2;++mv)
      #pragma unroll
      for (int r=0;r<4;++r){
        float x = acc[mv][nr][r] + bLds[wave*32 + mv*16 + lg*4 + r];
        xv[mv*4+r]=x; m = fmaxf(m,x);
      }
    float s=0.f;
    #pragma unroll
    for (int i=0;i<8;++i) s += __expf(xv[i]-m);
    #pragma unroll
    for (int d=16; d<=32; d<<=1){
      float om = __shfl_xor(m, d, 64);
      float os = __shfl_xor(s, d, 64);
      float nm = fmaxf(m, om);
      s = s*__expf(m-nm) + os*__expf(om-nm);
      m = nm;
    }
    if (lg == 0){
      pmLds[wave][nr*16+lr] = m;
      psLds[wave][nr*16+lr] = s;
    }
  }
  __syncthreads();
  if (tid < 128){
    float m=-1e30f;
    #pragma unroll
    for (int w=0;w<4;++w) m = fmaxf(m, pmLds[w][tid]);
    float s=0.f;
    #pragma unroll
    for (int w=0;w<4;++w) s += psLds[w][tid]*__expf(pmLds[w][tid]-m);
    pmax[(size_t)(r0+tid)*VTILES + vb] = m;
    psum[(size_t)(r0+tid)*VTILES + vb] = s;
  }
}

// ---------- target scores ----------
__global__ void k_tgt(const ushort_t* __restrict__ hall, const ushort_t* __restrict__ WoutT,
                      const float* __restrict__ b_out, const int* __restrict__ captions,
                      float* __restrict__ stgt) {
  int tid = threadIdx.x;
  int wave = tid>>6, lane = tid&63;
  int r = blockIdx.x*4 + wave;
  int n = r>>5, t = r&31;
  int y = captions[n*33 + t + 1];
  const ushort_t* hrow = hall + (size_t)r*1024;
  const ushort_t* wrow = WoutT + (size_t)y*1024;
  float dot = 0.f;
  #pragma unroll
  for (int i=0;i<2;++i){
    int off = lane*8 + i*512;
    short8 hv = *reinterpret_cast<const short8*>(&hrow[off]);
    short8 wv = *reinterpret_cast<const short8*>(&wrow[off]);
    #pragma unroll
    for (int e2=0;e2<8;++e2) dot += b2f((ushort_t)hv[e2])*b2f((ushort_t)wv[e2]);
  }
  #pragma unroll
  for (int d=32; d>=1; d>>=1) dot += __shfl_xor(dot, d, 64);
  if (lane==0) stgt[r] = dot + b_out[y];
}

// ---------- combine partials -> per-row masked nll ----------
__global__ void k_reduce(const float* __restrict__ pmax, const float* __restrict__ psum,
                         const float* __restrict__ stgt, const int* __restrict__ captions,
                         float* __restrict__ row_loss) {
  int tid = threadIdx.x;
  int wave = tid>>6, lane = tid&63;
  int r = blockIdx.x*4 + wave;
  float m = -1e30f, s = 0.f;
  for (int j = lane; j < VTILES; j += 64){
    float mj = pmax[(size_t)r*VTILES + j];
    float sj = psum[(size_t)r*VTILES + j];
    float nm = fmaxf(m, mj);
    s = s*__expf(m-nm) + sj*__expf(mj-nm);
    m = nm;
  }
  #pragma unroll
  for (int d=32; d>=1; d>>=1){
    float om = __shfl_xor(m, d, 64);
    float os = __shfl_xor(s, d, 64);
    float nm = fmaxf(m, om);
    s = s*__expf(m-nm) + os*__expf(om-nm);
    m = nm;
  }
  if (lane==0){
    int n = r>>5, t = r&31;
    int y = captions[n*33 + t + 1];
    float lse = m + __logf(s);
    row_loss[r] = (y != 0) ? (lse - stgt[r]) : 0.f;
  }
}

// ---------- final deterministic sum ----------
__global__ void k_final(const float* __restrict__ row_loss, float* __restrict__ out) {
  __shared__ float red[256];
  int tid = threadIdx.x;
  float s = 0.f;
  #pragma unroll
  for (int i=0;i<8;++i) s += row_loss[tid + i*256];
  red[tid] = s;
  __syncthreads();
  for (int off=128; off>=1; off>>=1){
    if (tid<off) red[tid] += red[tid+off];
    __syncthreads();
  }
  if (tid==0) out[0] = red[0] * (1.f/64.f);
}

extern "C" void kernel_launch(void* const* d_in, const int* in_sizes, int n_in,
                              void* d_out, int out_size, void* d_ws, size_t ws_size,
                              hipStream_t stream) {
  const float* features = (const float*)d_in[0];
  const int*   captions = (const int*)d_in[1];
  const float* W_embed  = (const float*)d_in[2];
  const float* Wx       = (const float*)d_in[3];
  const float* Wh       = (const float*)d_in[4];
  const float* Wattn    = (const float*)d_in[5];
  const float* b        = (const float*)d_in[6];
  const float* W_proj   = (const float*)d_in[7];
  const float* b_proj   = (const float*)d_in[8];
  const float* W_out    = (const float*)d_in[9];
  const float* b_out    = (const float*)d_in[10];
  float* out = (float*)d_out;

  char* wsp = (char*)d_ws;
  size_t off = 0;
  auto alloc = [&](size_t bytes)->char*{
    char* p = wsp + off; off += (bytes + 255) & ~(size_t)255; return p;
  };
  ushort_t* WcatT = (ushort_t*)alloc((size_t)4096*2560*2);
  ushort_t* WoutT = (ushort_t*)alloc((size_t)32000*1024*2);
  float* A_flat   = (float*)alloc((size_t)64*1024*16*4);
  ushort_t* xb    = (ushort_t*)alloc((size_t)64*32*512*2);
  float* hbuf     = (float*)alloc((size_t)64*1024*4);
  ushort_t* Pbuf  = (ushort_t*)alloc((size_t)64*4096*16*2);
  ushort_t* xpre  = (ushort_t*)alloc((size_t)2048*4096*2);
  float* a_part   = (float*)alloc((size_t)4*64*4096*4);
  ushort_t* hbf   = (ushort_t*)alloc((size_t)64*1024*2);
  float* cbuf     = (float*)alloc((size_t)64*1024*4);
  float* wvbuf    = (float*)alloc((size_t)64*16*4);
  ushort_t* hall  = (ushort_t*)alloc((size_t)2048*1024*2);
  float* pmax     = (float*)alloc((size_t)2048*250*4);
  float* psum     = (float*)alloc((size_t)2048*250*4);
  float* stgt     = (float*)alloc((size_t)2048*4);
  float* row_loss = (float*)alloc((size_t)2048*4);

  hipLaunchKernelGGL(k_transpose_cvt, dim3(64, 8),   dim3(256), 0, stream, Wx,    WcatT, 4096, 2560, 0);
  hipLaunchKernelGGL(k_transpose_cvt, dim3(64, 16),  dim3(256), 0, stream, Wh,    WcatT, 4096, 2560, 512);
  hipLaunchKernelGGL(k_transpose_cvt, dim3(64, 16),  dim3(256), 0, stream, Wattn, WcatT, 4096, 2560, 1536);
  hipLaunchKernelGGL(k_transpose_cvt, dim3(500, 16), dim3(256), 0, stream, W_out, WoutT, 32000, 1024, 0);
  hipLaunchKernelGGL(k_embed, dim3(1024), dim3(256), 0, stream, captions, W_embed, xb);
  hipLaunchKernelGGL(k_proj, dim3(4, 64), dim3(256), 0, stream, features, W_proj, b_proj, A_flat, hbuf);
  hipLaunchKernelGGL(k_pgemm, dim3(64, 64), dim3(256), 0, stream, A_flat, WcatT, Pbuf);
  hipLaunchKernelGGL(k_xmm, dim3(64, 32), dim3(256), 0, stream, WcatT, xb, xpre);

  for (int i = 0; i <= 32; ++i){
    hipLaunchKernelGGL(k_gate, dim3(64), dim3(256), 0, stream, i, xpre, a_part, b, Pbuf,
                       A_flat, hbuf, cbuf, wvbuf, hbf, hall);
    if (i < 32)
      hipLaunchKernelGGL(k_mm, dim3(64, 4), dim3(256), 0, stream, WcatT, hbf, a_part);
  }

  hipLaunchKernelGGL(k_score, dim3(4000), dim3(256), 0, stream, WoutT, hall, b_out, pmax, psum);
  hipLaunchKernelGGL(k_tgt, dim3(512), dim3(256), 0, stream, hall, WoutT, b_out, captions, stgt);
  hipLaunchKernelGGL(k_reduce, dim3(512), dim3(256), 0, stream, pmax, psum, stgt, captions, row_loss);
  hipLaunchKernelGGL(k_final, dim3(1), dim3(256), 0, stream, row_loss, out);
}

// Round 5
// 700.719 us; speedup vs baseline: 2.3938x; 1.2502x over previous
//
#include <hip/hip_runtime.h>
#include <hip/hip_bf16.h>
#include <math.h>

typedef __attribute__((ext_vector_type(8))) short short8;
typedef __attribute__((ext_vector_type(4))) float f32x4;
typedef unsigned short ushort_t;
typedef unsigned int uint_t;

typedef __attribute__((address_space(1))) const void gvoid_t;
typedef __attribute__((address_space(3))) void lvoid_t;

#define VTILES 250

static __device__ __forceinline__ ushort_t f2b(float f){
  __hip_bfloat16 h = __float2bfloat16(f);
  return *reinterpret_cast<ushort_t*>(&h);
}
static __device__ __forceinline__ float b2f(ushort_t u){
  __hip_bfloat16 h = *reinterpret_cast<__hip_bfloat16*>(&u);
  return __bfloat162float(h);
}
static __device__ __forceinline__ float sigmoidf_(float x){ return 1.0f/(1.0f+__expf(-x)); }

// ---------- transpose + f32->bf16 convert: dst[c][dcoloff + r] = src[r][c] ----------
__global__ void k_transpose_cvt(const float* __restrict__ src, ushort_t* __restrict__ dst,
                                int C, int dstride, int dcoloff) {
  __shared__ ushort_t tile[64][72];
  int cb = blockIdx.x * 64, rb = blockIdx.y * 64;
  int tid = threadIdx.x;
  for (int it = 0; it < 4; ++it) {
    int e = tid + it*256;
    int row = e >> 4;
    int seg = e & 15;
    float4 v = *reinterpret_cast<const float4*>(&src[(size_t)(rb+row)*C + cb + seg*4]);
    tile[seg*4+0][row] = f2b(v.x);
    tile[seg*4+1][row] = f2b(v.y);
    tile[seg*4+2][row] = f2b(v.z);
    tile[seg*4+3][row] = f2b(v.w);
  }
  __syncthreads();
  for (int it = 0; it < 2; ++it) {
    int e = tid + it*256;
    int cl = e >> 3;
    int seg = e & 7;
    uint4 v = *reinterpret_cast<uint4*>(&tile[cl][seg*8]);
    *reinterpret_cast<uint4*>(&dst[(size_t)(cb+cl)*dstride + dcoloff + rb + seg*8]) = v;
  }
}

// ---------- features [n][d][16] f32 -> fBT [(n*16+p)][d] bf16 ----------
__global__ void k_featT(const float* __restrict__ feat, ushort_t* __restrict__ fBT) {
  __shared__ ushort_t t[16][264];
  int n = blockIdx.x;
  int tid = threadIdx.x;
  for (int it = 0; it < 4; ++it) {
    int d = it*256 + tid;
    const float* src = &feat[((size_t)n*1024 + d)*16];
    #pragma unroll
    for (int q = 0; q < 4; ++q) {
      float4 v = *reinterpret_cast<const float4*>(&src[q*4]);
      t[q*4+0][tid] = f2b(v.x);
      t[q*4+1][tid] = f2b(v.y);
      t[q*4+2][tid] = f2b(v.z);
      t[q*4+3][tid] = f2b(v.w);
    }
    __syncthreads();
    #pragma unroll
    for (int w = 0; w < 2; ++w) {
      int e = tid + w*256;           // 0..511
      int p = e >> 5;                // 0..15
      int seg = e & 31;              // 32 segs x 8 bf16
      uint4 v = *reinterpret_cast<uint4*>(&t[p][seg*8]);
      *reinterpret_cast<uint4*>(&fBT[((size_t)n*16 + p)*1024 + it*256 + seg*8]) = v;
    }
    __syncthreads();
  }
}

// ---------- embedding gather -> bf16 ----------
__global__ void k_embed(const int* __restrict__ captions, const float* __restrict__ W_embed,
                        ushort_t* __restrict__ xb) {
  int e = (blockIdx.x*256 + threadIdx.x) * 4;
  int nt = e >> 9;
  int n = nt >> 5, t = nt & 31;
  int col = e & 511;
  int tok = captions[n*33 + t];
  float4 v = *reinterpret_cast<const float4*>(&W_embed[(size_t)tok*512 + col]);
  ushort4 o; o.x=f2b(v.x); o.y=f2b(v.y); o.z=f2b(v.z); o.w=f2b(v.w);
  *reinterpret_cast<ushort4*>(&xb[e]) = o;
}

// ---------- A_flat/Abt = WprojT @ fBT^T + b_proj  (MFMA GEMM, 64x64 tiles) ----------
__global__ void k_projmm(const ushort_t* __restrict__ WprojT, const ushort_t* __restrict__ fBT,
                         const float* __restrict__ b_proj, float* __restrict__ A_flat,
                         ushort_t* __restrict__ Abt) {
  __shared__ ushort_t As[64*64];
  __shared__ ushort_t Bs[64*64];
  int kt = blockIdx.x, nt = blockIdx.y;
  int k0 = kt*64, n0 = nt*64;
  int tid = threadIdx.x;
  int wave = tid>>6, lane = tid&63, lr = lane&15, lg = lane>>4;
  int srow = lane>>3, sxor8 = ((lane&7)^srow)*8;
  f32x4 acc[4];
  #pragma unroll
  for (int nf=0;nf<4;++nf) acc[nf] = (f32x4){0.f,0.f,0.f,0.f};
  for (int kc = 0; kc < 1024; kc += 64){
    __syncthreads();
    #pragma unroll
    for (int u = 0; u < 2; ++u){
      int r0 = wave*16 + u*8;
      const ushort_t* srcA = &WprojT[(size_t)(k0 + r0 + srow)*1024 + kc + sxor8];
      const ushort_t* srcB = &fBT[(size_t)(n0 + r0 + srow)*1024 + kc + sxor8];
      __builtin_amdgcn_global_load_lds((gvoid_t*)srcA, (lvoid_t*)&As[r0*64], 16, 0, 0);
      __builtin_amdgcn_global_load_lds((gvoid_t*)srcB, (lvoid_t*)&Bs[r0*64], 16, 0, 0);
    }
    __syncthreads();
    #pragma unroll
    for (int kk = 0; kk < 2; ++kk){
      int swz = (((kk*4 + lg) ^ (lr & 7)) * 8);
      short8 af = *reinterpret_cast<short8*>(&As[(wave*16 + lr)*64 + swz]);
      #pragma unroll
      for (int nf = 0; nf < 4; ++nf){
        short8 bf = *reinterpret_cast<short8*>(&Bs[(nf*16 + lr)*64 + swz]);
        acc[nf] = __builtin_amdgcn_mfma_f32_16x16x32_bf16(af, bf, acc[nf], 0, 0, 0);
      }
    }
  }
  #pragma unroll
  for (int nf=0;nf<4;++nf){
    int ncol = n0 + nf*16 + lr;
    int nidx = ncol >> 4, p = ncol & 15;
    ushort4 ab;
    #pragma unroll
    for (int r=0;r<4;++r){
      int kh = k0 + wave*16 + lg*4 + r;
      float val = acc[nf][r] + b_proj[kh];
      A_flat[((size_t)nidx*1024 + kh)*16 + p] = val;
      (&ab.x)[r] = f2b(val);
    }
    *reinterpret_cast<ushort4*>(&Abt[(size_t)ncol*1024 + k0 + wave*16 + lg*4]) = ab;
  }
}

// ---------- h0 = mean over p ----------
__global__ void k_h0(const float* __restrict__ A_flat, float* __restrict__ hbuf) {
  int idx = blockIdx.x*256 + threadIdx.x;
  const float* a = &A_flat[(size_t)idx*16];
  float s = 0.f;
  #pragma unroll
  for (int p=0;p<16;p+=4){
    float4 v = *reinterpret_cast<const float4*>(&a[p]);
    s += v.x+v.y+v.z+v.w;
  }
  hbuf[idx] = s * (1.f/16.f);
}

// ---------- P2[j][n*16+p] = sum_k Wattn[k][j] * A_flat[n][k][p]  (MFMA GEMM) ----------
__global__ void k_pmm(const ushort_t* __restrict__ WcatT, const ushort_t* __restrict__ Abt,
                      ushort_t* __restrict__ P2) {
  __shared__ ushort_t As[64*64];
  __shared__ ushort_t Bs[64*64];
  __shared__ ushort_t Dt2[64][72];
  int jt = blockIdx.x, nt = blockIdx.y;
  int j0 = jt*64, n0 = nt*64;
  int tid = threadIdx.x;
  int wave = tid>>6, lane = tid&63, lr = lane&15, lg = lane>>4;
  int srow = lane>>3, sxor8 = ((lane&7)^srow)*8;
  f32x4 acc[4];
  #pragma unroll
  for (int nf=0;nf<4;++nf) acc[nf] = (f32x4){0.f,0.f,0.f,0.f};
  for (int kc = 0; kc < 1024; kc += 64){
    __syncthreads();
    #pragma unroll
    for (int u = 0; u < 2; ++u){
      int r0 = wave*16 + u*8;
      const ushort_t* srcA = &WcatT[(size_t)(j0 + r0 + srow)*2560 + 1536 + kc + sxor8];
      const ushort_t* srcB = &Abt[(size_t)(n0 + r0 + srow)*1024 + kc + sxor8];
      __builtin_amdgcn_global_load_lds((gvoid_t*)srcA, (lvoid_t*)&As[r0*64], 16, 0, 0);
      __builtin_amdgcn_global_load_lds((gvoid_t*)srcB, (lvoid_t*)&Bs[r0*64], 16, 0, 0);
    }
    __syncthreads();
    #pragma unroll
    for (int kk = 0; kk < 2; ++kk){
      int swz = (((kk*4 + lg) ^ (lr & 7)) * 8);
      short8 af = *reinterpret_cast<short8*>(&As[(wave*16 + lr)*64 + swz]);
      #pragma unroll
      for (int nf = 0; nf < 4; ++nf){
        short8 bf = *reinterpret_cast<short8*>(&Bs[(nf*16 + lr)*64 + swz]);
        acc[nf] = __builtin_amdgcn_mfma_f32_16x16x32_bf16(af, bf, acc[nf], 0, 0, 0);
      }
    }
  }
  __syncthreads();
  #pragma unroll
  for (int nf=0;nf<4;++nf)
    #pragma unroll
    for (int r=0;r<4;++r)
      Dt2[wave*16 + lg*4 + r][nf*16 + lr] = f2b(acc[nf][r]);
  __syncthreads();
  #pragma unroll
  for (int it=0; it<2; ++it){
    int e = it*256 + tid;          // 0..511
    int row = e >> 3, seg = e & 7; // 64 rows x 8 segs(8 bf16)
    uint4 v = *reinterpret_cast<uint4*>(&Dt2[row][seg*8]);
    *reinterpret_cast<uint4*>(&P2[(size_t)(j0+row)*1024 + n0 + seg*8]) = v;
  }
}

// ---------- xpre[nt][j] = xb @ Wx ----------
__global__ void k_xmm(const ushort_t* __restrict__ WcatT, const ushort_t* __restrict__ xb,
                      ushort_t* __restrict__ xpre) {
  __shared__ ushort_t As[64*64];
  __shared__ ushort_t Bs[64*64];
  __shared__ float Dt[64][68];
  int jt = blockIdx.x, mt = blockIdx.y;
  int j0 = jt*64, m0 = mt*64;
  int tid = threadIdx.x;
  int wave = tid>>6, lane = tid&63, lr = lane&15, lg = lane>>4;
  int srow = lane>>3, sxor8 = ((lane&7)^srow)*8;
  f32x4 acc[4];
  #pragma unroll
  for (int nf=0;nf<4;++nf) acc[nf] = (f32x4){0.f,0.f,0.f,0.f};
  for (int kc = 0; kc < 512; kc += 64){
    __syncthreads();
    #pragma unroll
    for (int u = 0; u < 2; ++u){
      int r0 = wave*16 + u*8;
      const ushort_t* srcA = &WcatT[(size_t)(j0 + r0 + srow)*2560 + kc + sxor8];
      const ushort_t* srcB = &xb[(size_t)(m0 + r0 + srow)*512 + kc + sxor8];
      __builtin_amdgcn_global_load_lds((gvoid_t*)srcA, (lvoid_t*)&As[r0*64], 16, 0, 0);
      __builtin_amdgcn_global_load_lds((gvoid_t*)srcB, (lvoid_t*)&Bs[r0*64], 16, 0, 0);
    }
    __syncthreads();
    #pragma unroll
    for (int kk = 0; kk < 2; ++kk){
      int swz = (((kk*4 + lg) ^ (lr & 7)) * 8);
      short8 af = *reinterpret_cast<short8*>(&As[(wave*16 + lr)*64 + swz]);
      #pragma unroll
      for (int nf = 0; nf < 4; ++nf){
        short8 bf = *reinterpret_cast<short8*>(&Bs[(nf*16 + lr)*64 + swz]);
        acc[nf] = __builtin_amdgcn_mfma_f32_16x16x32_bf16(af, bf, acc[nf], 0, 0, 0);
      }
    }
  }
  __syncthreads();
  #pragma unroll
  for (int nf=0; nf<4; ++nf)
    #pragma unroll
    for (int r=0;r<4;++r)
      Dt[nf*16+lr][wave*16 + lg*4 + r] = acc[nf][r];
  __syncthreads();
  #pragma unroll
  for (int it=0; it<4; ++it){
    int e = tid + it*256;
    int nrow = e >> 4, seg = e & 15;
    float4 v = *reinterpret_cast<float4*>(&Dt[nrow][seg*4]);
    ushort4 o; o.x=f2b(v.x); o.y=f2b(v.y); o.z=f2b(v.z); o.w=f2b(v.w);
    *reinterpret_cast<ushort4*>(&xpre[(size_t)(m0+nrow)*4096 + j0 + seg*4]) = o;
  }
}

// ---------- per-step gates + c/h update + score partials (256 blocks) ----------
__global__ void k_gate(int i, const ushort_t* __restrict__ xpre, const float* __restrict__ a_part,
                       const float* __restrict__ bvec, const ushort_t* __restrict__ P2,
                       const float* __restrict__ A_flat, const float* __restrict__ hbuf,
                       float* __restrict__ cbuf, const float* __restrict__ sp_rd,
                       float* __restrict__ sp_wr, ushort_t* __restrict__ hbf,
                       ushort_t* __restrict__ hall) {
  __shared__ float wvLds[16];
  __shared__ float wred[4][16];
  int n = blockIdx.x >> 2, sp = blockIdx.x & 3;
  int tid = threadIdx.x;
  int wave = tid>>6, lane = tid&63;
  int k = sp*256 + tid;
  float hv;
  if (i == 0){
    hv = hbuf[n*1024 + k];
    cbuf[n*1024 + k] = hv;
    hbf[n*1024 + k] = f2b(hv);
  } else {
    if (tid < 16){
      float sv = (sp_rd[(n*4+0)*16+tid] + sp_rd[(n*4+1)*16+tid] +
                  sp_rd[(n*4+2)*16+tid] + sp_rd[(n*4+3)*16+tid]) * (1.f/32.f);
      float m = sv;
      #pragma unroll
      for (int d=1; d<16; d<<=1) m = fmaxf(m, __shfl_xor(m, d, 64));
      float e = __expf(sv - m);
      float s = e;
      #pragma unroll
      for (int d=1; d<16; d<<=1) s += __shfl_xor(s, d, 64);
      wvLds[tid] = e / s;
    }
    __syncthreads();
    float wv[16];
    #pragma unroll
    for (int p=0;p<16;++p) wv[p] = wvLds[p];
    float av[4];
    #pragma unroll
    for (int g=0;g<4;++g){
      int j = g*1024 + k;
      float x = bvec[j] + b2f(xpre[(size_t)(n*32 + (i-1))*4096 + j]);
      #pragma unroll
      for (int ks=0;ks<4;++ks) x += a_part[((size_t)ks*64 + n)*4096 + j];
      const ushort_t* pp = &P2[(size_t)j*1024 + (n<<4)];
      short8 p0 = *reinterpret_cast<const short8*>(pp);
      short8 p1 = *reinterpret_cast<const short8*>(pp+8);
      #pragma unroll
      for (int p=0;p<8;++p) x += wv[p]*b2f((ushort_t)p0[p]);
      #pragma unroll
      for (int p=0;p<8;++p) x += wv[8+p]*b2f((ushort_t)p1[p]);
      av[g]=x;
    }
    float ig=sigmoidf_(av[0]), fg=sigmoidf_(av[1]), og=sigmoidf_(av[2]), gg=tanhf(av[3]);
    float c = fg*cbuf[n*1024+k] + ig*gg;
    hv = og*tanhf(c);
    cbuf[n*1024+k] = c;
    hall[((size_t)n*32 + (i-1))*1024 + k] = f2b(hv);
    if (i < 32) hbf[n*1024+k] = f2b(hv);
  }
  if (i == 32) return;
  // score partials: spart[n][sp][p] = sum_{k in chunk} h[k] * A_flat[n][k][p]
  float sacc[16];
  const float* An = &A_flat[((size_t)n*1024 + k)*16];
  #pragma unroll
  for (int p=0;p<16;p+=4){
    float4 a4 = *reinterpret_cast<const float4*>(&An[p]);
    sacc[p] = hv*a4.x; sacc[p+1] = hv*a4.y; sacc[p+2] = hv*a4.z; sacc[p+3] = hv*a4.w;
  }
  #pragma unroll
  for (int d=1; d<64; d<<=1)
    #pragma unroll
    for (int p=0;p<16;++p) sacc[p] += __shfl_xor(sacc[p], d, 64);
  if (lane == 0)
    #pragma unroll
    for (int p=0;p<16;++p) wred[wave][p] = sacc[p];
  __syncthreads();
  if (tid < 16)
    sp_wr[(n*4+sp)*16 + tid] = wred[0][tid]+wred[1][tid]+wred[2][tid]+wred[3][tid];
}

// ---------- a_part[ks] = h @ Wh (K-chunk ks of 256) ----------
__global__ void k_mm(const ushort_t* __restrict__ WcatT, const ushort_t* __restrict__ hbf,
                     float* __restrict__ a_part) {
  __shared__ ushort_t As[64*64];
  __shared__ ushort_t Bs[64*64];
  __shared__ float Dt[64][68];
  int jt = blockIdx.x, ks = blockIdx.y;
  int j0 = jt*64;
  int tid = threadIdx.x;
  int wave = tid>>6, lane = tid&63, lr = lane&15, lg = lane>>4;
  int srow = lane>>3, sxor8 = ((lane&7)^srow)*8;
  f32x4 acc[4];
  #pragma unroll
  for (int nf=0;nf<4;++nf) acc[nf] = (f32x4){0.f,0.f,0.f,0.f};
  for (int kc = 0; kc < 256; kc += 64){
    __syncthreads();
    #pragma unroll
    for (int u = 0; u < 2; ++u){
      int r0 = wave*16 + u*8;
      const ushort_t* srcA = &WcatT[(size_t)(j0 + r0 + srow)*2560 + 512 + ks*256 + kc + sxor8];
      const ushort_t* srcB = &hbf[(size_t)(r0 + srow)*1024 + ks*256 + kc + sxor8];
      __builtin_amdgcn_global_load_lds((gvoid_t*)srcA, (lvoid_t*)&As[r0*64], 16, 0, 0);
      __builtin_amdgcn_global_load_lds((gvoid_t*)srcB, (lvoid_t*)&Bs[r0*64], 16, 0, 0);
    }
    __syncthreads();
    #pragma unroll
    for (int kk = 0; kk < 2; ++kk){
      int swz = (((kk*4 + lg) ^ (lr & 7)) * 8);
      short8 af = *reinterpret_cast<short8*>(&As[(wave*16 + lr)*64 + swz]);
      #pragma unroll
      for (int nf = 0; nf < 4; ++nf){
        short8 bf = *reinterpret_cast<short8*>(&Bs[(nf*16 + lr)*64 + swz]);
        acc[nf] = __builtin_amdgcn_mfma_f32_16x16x32_bf16(af, bf, acc[nf], 0, 0, 0);
      }
    }
  }
  __syncthreads();
  #pragma unroll
  for (int nf=0; nf<4; ++nf)
    #pragma unroll
    for (int r=0;r<4;++r)
      Dt[nf*16+lr][wave*16 + lg*4 + r] = acc[nf][r];
  __syncthreads();
  #pragma unroll
  for (int it=0; it<4; ++it){
    int e = tid + it*256;
    int nrow = e >> 4, seg = e & 15;
    float4 v = *reinterpret_cast<float4*>(&Dt[nrow][seg*4]);
    *reinterpret_cast<float4*>(&a_part[((size_t)ks*64 + nrow)*4096 + j0 + seg*4]) = v;
  }
}

// ---------- scores tile + fused partial logsumexp over 128-v tile ----------
__global__ void __launch_bounds__(256, 4)
k_score(const ushort_t* __restrict__ WoutT, const ushort_t* __restrict__ hall,
        const float* __restrict__ b_out,
        float* __restrict__ pmax, float* __restrict__ psum) {
  __shared__ ushort_t As[128*64];
  __shared__ ushort_t Bs[128*64];
  __shared__ float bLds[128];
  __shared__ float pmLds[4][128];
  __shared__ float psLds[4][128];
  int bid = blockIdx.x;
  int wg = (bid & 7) * 500 + (bid >> 3);
  int vb = wg >> 4, rb = wg & 15;
  int v0 = vb * 128, r0 = rb * 128;
  int tid = threadIdx.x;
  int wave = tid >> 6, lane = tid & 63, lr = lane & 15, lg = lane >> 4;
  if (tid < 128) bLds[tid] = b_out[v0 + tid];

  int srow = lane >> 3;
  int sxor = ((lane & 7) ^ srow) << 3;

  f32x4 acc[2][8];
  #pragma unroll
  for (int a=0;a<2;++a)
    #pragma unroll
    for (int q=0;q<8;++q) acc[a][q]=(f32x4){0.f,0.f,0.f,0.f};

  for (int kc = 0; kc < 1024; kc += 64) {
    __syncthreads();
    #pragma unroll
    for (int i = 0; i < 4; ++i) {
      int rowg = (wave*4 + i) * 8;
      const ushort_t* gsA = &WoutT[(size_t)(v0 + rowg + srow)*1024 + kc + sxor];
      const ushort_t* gsB = &hall [(size_t)(r0 + rowg + srow)*1024 + kc + sxor];
      __builtin_amdgcn_global_load_lds((gvoid_t*)gsA, (lvoid_t*)&As[rowg*64], 16, 0, 0);
      __builtin_amdgcn_global_load_lds((gvoid_t*)gsB, (lvoid_t*)&Bs[rowg*64], 16, 0, 0);
    }
    __syncthreads();
    #pragma unroll
    for (int kk = 0; kk < 2; ++kk) {
      int swz = ((kk*4 + lg) ^ (lr & 7)) << 3;
      int rowA = wave*32 + lr;
      short8 af0 = *reinterpret_cast<short8*>(&As[rowA*64 + swz]);
      short8 af1 = *reinterpret_cast<short8*>(&As[(rowA+16)*64 + swz]);
      #pragma unroll
      for (int nr = 0; nr < 8; ++nr) {
        short8 bf = *reinterpret_cast<short8*>(&Bs[(nr*16+lr)*64 + swz]);
        acc[0][nr] = __builtin_amdgcn_mfma_f32_16x16x32_bf16(af0, bf, acc[0][nr], 0,0,0);
        acc[1][nr] = __builtin_amdgcn_mfma_f32_16x16x32_bf16(af1, bf, acc[1][nr], 0,0,0);
      }
    }
  }
  #pragma unroll
  for (int nr=0;nr<8;++nr){
    float m = -1e30f;
    float xv[8];
    #pragma unroll
    for (int mv=0;mv<2;++mv)
      #pragma unroll
      for (int r=0;r<4;++r){
        float x = acc[mv][nr][r] + bLds[wave*32 + mv*16 + lg*4 + r];
        xv[mv*4+r]=x; m = fmaxf(m,x);
      }
    float s=0.f;
    #pragma unroll
    for (int i=0;i<8;++i) s += __expf(xv[i]-m);
    #pragma unroll
    for (int d=16; d<=32; d<<=1){
      float om = __shfl_xor(m, d, 64);
      float os = __shfl_xor(s, d, 64);
      float nm = fmaxf(m, om);
      s = s*__expf(m-nm) + os*__expf(om-nm);
      m = nm;
    }
    if (lg == 0){
      pmLds[wave][nr*16+lr] = m;
      psLds[wave][nr*16+lr] = s;
    }
  }
  __syncthreads();
  if (tid < 128){
    float m=-1e30f;
    #pragma unroll
    for (int w=0;w<4;++w) m = fmaxf(m, pmLds[w][tid]);
    float s=0.f;
    #pragma unroll
    for (int w=0;w<4;++w) s += psLds[w][tid]*__expf(pmLds[w][tid]-m);
    pmax[(size_t)(r0+tid)*VTILES + vb] = m;
    psum[(size_t)(r0+tid)*VTILES + vb] = s;
  }
}

// ---------- target scores ----------
__global__ void k_tgt(const ushort_t* __restrict__ hall, const ushort_t* __restrict__ WoutT,
                      const float* __restrict__ b_out, const int* __restrict__ captions,
                      float* __restrict__ stgt) {
  int tid = threadIdx.x;
  int wave = tid>>6, lane = tid&63;
  int r = blockIdx.x*4 + wave;
  int n = r>>5, t = r&31;
  int y = captions[n*33 + t + 1];
  const ushort_t* hrow = hall + (size_t)r*1024;
  const ushort_t* wrow = WoutT + (size_t)y*1024;
  float dot = 0.f;
  #pragma unroll
  for (int i=0;i<2;++i){
    int off = lane*8 + i*512;
    short8 hv = *reinterpret_cast<const short8*>(&hrow[off]);
    short8 wv = *reinterpret_cast<const short8*>(&wrow[off]);
    #pragma unroll
    for (int e2=0;e2<8;++e2) dot += b2f((ushort_t)hv[e2])*b2f((ushort_t)wv[e2]);
  }
  #pragma unroll
  for (int d=32; d>=1; d>>=1) dot += __shfl_xor(dot, d, 64);
  if (lane==0) stgt[r] = dot + b_out[y];
}

// ---------- combine partials -> per-row masked nll ----------
__global__ void k_reduce(const float* __restrict__ pmax, const float* __restrict__ psum,
                         const float* __restrict__ stgt, const int* __restrict__ captions,
                         float* __restrict__ row_loss) {
  int tid = threadIdx.x;
  int wave = tid>>6, lane = tid&63;
  int r = blockIdx.x*4 + wave;
  float m = -1e30f, s = 0.f;
  for (int j = lane; j < VTILES; j += 64){
    float mj = pmax[(size_t)r*VTILES + j];
    float sj = psum[(size_t)r*VTILES + j];
    float nm = fmaxf(m, mj);
    s = s*__expf(m-nm) + sj*__expf(mj-nm);
    m = nm;
  }
  #pragma unroll
  for (int d=32; d>=1; d>>=1){
    float om = __shfl_xor(m, d, 64);
    float os = __shfl_xor(s, d, 64);
    float nm = fmaxf(m, om);
    s = s*__expf(m-nm) + os*__expf(om-nm);
    m = nm;
  }
  if (lane==0){
    int n = r>>5, t = r&31;
    int y = captions[n*33 + t + 1];
    float lse = m + __logf(s);
    row_loss[r] = (y != 0) ? (lse - stgt[r]) : 0.f;
  }
}

// ---------- final deterministic sum ----------
__global__ void k_final(const float* __restrict__ row_loss, float* __restrict__ out) {
  __shared__ float red[256];
  int tid = threadIdx.x;
  float s = 0.f;
  #pragma unroll
  for (int i=0;i<8;++i) s += row_loss[tid + i*256];
  red[tid] = s;
  __syncthreads();
  for (int off=128; off>=1; off>>=1){
    if (tid<off) red[tid] += red[tid+off];
    __syncthreads();
  }
  if (tid==0) out[0] = red[0] * (1.f/64.f);
}

extern "C" void kernel_launch(void* const* d_in, const int* in_sizes, int n_in,
                              void* d_out, int out_size, void* d_ws, size_t ws_size,
                              hipStream_t stream) {
  const float* features = (const float*)d_in[0];
  const int*   captions = (const int*)d_in[1];
  const float* W_embed  = (const float*)d_in[2];
  const float* Wx       = (const float*)d_in[3];
  const float* Wh       = (const float*)d_in[4];
  const float* Wattn    = (const float*)d_in[5];
  const float* b        = (const float*)d_in[6];
  const float* W_proj   = (const float*)d_in[7];
  const float* b_proj   = (const float*)d_in[8];
  const float* W_out    = (const float*)d_in[9];
  const float* b_out    = (const float*)d_in[10];
  float* out = (float*)d_out;

  char* wsp = (char*)d_ws;
  size_t off = 0;
  auto alloc = [&](size_t bytes)->char*{
    char* p = wsp + off; off += (bytes + 255) & ~(size_t)255; return p;
  };
  ushort_t* WcatT  = (ushort_t*)alloc((size_t)4096*2560*2);
  ushort_t* WoutT  = (ushort_t*)alloc((size_t)32000*1024*2);
  ushort_t* WprojT = (ushort_t*)alloc((size_t)1024*1024*2);
  ushort_t* fBT    = (ushort_t*)alloc((size_t)1024*1024*2);
  ushort_t* Abt    = (ushort_t*)alloc((size_t)1024*1024*2);
  float* A_flat    = (float*)alloc((size_t)64*1024*16*4);
  ushort_t* xb     = (ushort_t*)alloc((size_t)64*32*512*2);
  float* hbuf      = (float*)alloc((size_t)64*1024*4);
  ushort_t* P2     = (ushort_t*)alloc((size_t)4096*1024*2);
  ushort_t* xpre   = (ushort_t*)alloc((size_t)2048*4096*2);
  float* a_part    = (float*)alloc((size_t)4*64*4096*4);
  ushort_t* hbf    = (ushort_t*)alloc((size_t)64*1024*2);
  float* cbuf      = (float*)alloc((size_t)64*1024*4);
  float* spbuf     = (float*)alloc((size_t)2*64*4*16*4);
  ushort_t* hall   = (ushort_t*)alloc((size_t)2048*1024*2);
  float* pmax      = (float*)alloc((size_t)2048*250*4);
  float* psum      = (float*)alloc((size_t)2048*250*4);
  float* stgt      = (float*)alloc((size_t)2048*4);
  float* row_loss  = (float*)alloc((size_t)2048*4);

  hipLaunchKernelGGL(k_transpose_cvt, dim3(64, 8),   dim3(256), 0, stream, Wx,     WcatT,  4096, 2560, 0);
  hipLaunchKernelGGL(k_transpose_cvt, dim3(64, 16),  dim3(256), 0, stream, Wh,     WcatT,  4096, 2560, 512);
  hipLaunchKernelGGL(k_transpose_cvt, dim3(64, 16),  dim3(256), 0, stream, Wattn,  WcatT,  4096, 2560, 1536);
  hipLaunchKernelGGL(k_transpose_cvt, dim3(500, 16), dim3(256), 0, stream, W_out,  WoutT,  32000, 1024, 0);
  hipLaunchKernelGGL(k_transpose_cvt, dim3(16, 16),  dim3(256), 0, stream, W_proj, WprojT, 1024, 1024, 0);
  hipLaunchKernelGGL(k_featT, dim3(64), dim3(256), 0, stream, features, fBT);
  hipLaunchKernelGGL(k_embed, dim3(1024), dim3(256), 0, stream, captions, W_embed, xb);
  hipLaunchKernelGGL(k_projmm, dim3(16, 16), dim3(256), 0, stream, WprojT, fBT, b_proj, A_flat, Abt);
  hipLaunchKernelGGL(k_h0, dim3(256), dim3(256), 0, stream, A_flat, hbuf);
  hipLaunchKernelGGL(k_pmm, dim3(64, 16), dim3(256), 0, stream, WcatT, Abt, P2);
  hipLaunchKernelGGL(k_xmm, dim3(64, 32), dim3(256), 0, stream, WcatT, xb, xpre);

  for (int i = 0; i <= 32; ++i){
    const float* sp_rd = spbuf + ((i+1)&1)*4096;
    float*       sp_wr = spbuf + (i&1)*4096;
    hipLaunchKernelGGL(k_gate, dim3(256), dim3(256), 0, stream, i, xpre, a_part, b, P2,
                       A_flat, hbuf, cbuf, sp_rd, sp_wr, hbf, hall);
    if (i < 32)
      hipLaunchKernelGGL(k_mm, dim3(64, 4), dim3(256), 0, stream, WcatT, hbf, a_part);
  }

  hipLaunchKernelGGL(k_score, dim3(4000), dim3(256), 0, stream, WoutT, hall, b_out, pmax, psum);
  hipLaunchKernelGGL(k_tgt, dim3(512), dim3(256), 0, stream, hall, WoutT, b_out, captions, stgt);
  hipLaunchKernelGGL(k_reduce, dim3(512), dim3(256), 0, stream, pmax, psum, stgt, captions, row_loss);
  hipLaunchKernelGGL(k_final, dim3(1), dim3(256), 0, stream, row_loss, out);
}

// Round 6
// 673.072 us; speedup vs baseline: 2.4921x; 1.0411x over previous
//
#include <hip/hip_runtime.h>
#include <hip/hip_bf16.h>
#include <math.h>

typedef __attribute__((ext_vector_type(8))) short short8;
typedef __attribute__((ext_vector_type(4))) float f32x4;
typedef unsigned short ushort_t;
typedef unsigned int uint_t;

typedef __attribute__((address_space(1))) const void gvoid_t;
typedef __attribute__((address_space(3))) void lvoid_t;

#define VTILES 250

static __device__ __forceinline__ ushort_t f2b(float f){
  __hip_bfloat16 h = __float2bfloat16(f);
  return *reinterpret_cast<ushort_t*>(&h);
}
static __device__ __forceinline__ float b2f(ushort_t u){
  __hip_bfloat16 h = *reinterpret_cast<__hip_bfloat16*>(&u);
  return __bfloat162float(h);
}
static __device__ __forceinline__ float sigmoidf_(float x){ return 1.0f/(1.0f+__expf(-x)); }

// ---------- transpose + f32->bf16 convert: dst[c][dcoloff + r] = src[r][c] ----------
__global__ void k_transpose_cvt(const float* __restrict__ src, ushort_t* __restrict__ dst,
                                int C, int dstride, int dcoloff) {
  __shared__ ushort_t tile[64][72];
  int cb = blockIdx.x * 64, rb = blockIdx.y * 64;
  int tid = threadIdx.x;
  for (int it = 0; it < 4; ++it) {
    int e = tid + it*256;
    int row = e >> 4;
    int seg = e & 15;
    float4 v = *reinterpret_cast<const float4*>(&src[(size_t)(rb+row)*C + cb + seg*4]);
    tile[seg*4+0][row] = f2b(v.x);
    tile[seg*4+1][row] = f2b(v.y);
    tile[seg*4+2][row] = f2b(v.z);
    tile[seg*4+3][row] = f2b(v.w);
  }
  __syncthreads();
  for (int it = 0; it < 2; ++it) {
    int e = tid + it*256;
    int cl = e >> 3;
    int seg = e & 7;
    uint4 v = *reinterpret_cast<uint4*>(&tile[cl][seg*8]);
    *reinterpret_cast<uint4*>(&dst[(size_t)(cb+cl)*dstride + dcoloff + rb + seg*8]) = v;
  }
}

// ---------- features [n][d][16] f32 -> fBT [(n*16+p)][d] bf16 ----------
__global__ void k_featT(const float* __restrict__ feat, ushort_t* __restrict__ fBT) {
  __shared__ ushort_t t[16][264];
  int n = blockIdx.x;
  int tid = threadIdx.x;
  for (int it = 0; it < 4; ++it) {
    int d = it*256 + tid;
    const float* src = &feat[((size_t)n*1024 + d)*16];
    #pragma unroll
    for (int q = 0; q < 4; ++q) {
      float4 v = *reinterpret_cast<const float4*>(&src[q*4]);
      t[q*4+0][tid] = f2b(v.x);
      t[q*4+1][tid] = f2b(v.y);
      t[q*4+2][tid] = f2b(v.z);
      t[q*4+3][tid] = f2b(v.w);
    }
    __syncthreads();
    #pragma unroll
    for (int w = 0; w < 2; ++w) {
      int e = tid + w*256;           // 0..511
      int p = e >> 5;                // 0..15
      int seg = e & 31;              // 32 segs x 8 bf16
      uint4 v = *reinterpret_cast<uint4*>(&t[p][seg*8]);
      *reinterpret_cast<uint4*>(&fBT[((size_t)n*16 + p)*1024 + it*256 + seg*8]) = v;
    }
    __syncthreads();
  }
}

// ---------- embedding gather -> bf16 ----------
__global__ void k_embed(const int* __restrict__ captions, const float* __restrict__ W_embed,
                        ushort_t* __restrict__ xb) {
  int e = (blockIdx.x*256 + threadIdx.x) * 4;
  int nt = e >> 9;
  int n = nt >> 5, t = nt & 31;
  int col = e & 511;
  int tok = captions[n*33 + t];
  float4 v = *reinterpret_cast<const float4*>(&W_embed[(size_t)tok*512 + col]);
  ushort4 o; o.x=f2b(v.x); o.y=f2b(v.y); o.z=f2b(v.z); o.w=f2b(v.w);
  *reinterpret_cast<ushort4*>(&xb[e]) = o;
}

// ---------- A_flat/Abt = WprojT @ fBT^T + b_proj ; h0 fused (MFMA GEMM) ----------
__global__ void k_projmm(const ushort_t* __restrict__ WprojT, const ushort_t* __restrict__ fBT,
                         const float* __restrict__ b_proj, float* __restrict__ A_flat,
                         ushort_t* __restrict__ Abt, float* __restrict__ hbuf) {
  __shared__ ushort_t As[64*64];
  __shared__ ushort_t Bs[64*64];
  int kt = blockIdx.x, nt = blockIdx.y;
  int k0 = kt*64, n0 = nt*64;
  int tid = threadIdx.x;
  int wave = tid>>6, lane = tid&63, lr = lane&15, lg = lane>>4;
  int srow = lane>>3, sxor8 = ((lane&7)^srow)*8;
  f32x4 acc[4];
  #pragma unroll
  for (int nf=0;nf<4;++nf) acc[nf] = (f32x4){0.f,0.f,0.f,0.f};
  for (int kc = 0; kc < 1024; kc += 64){
    __syncthreads();
    #pragma unroll
    for (int u = 0; u < 2; ++u){
      int r0 = wave*16 + u*8;
      const ushort_t* srcA = &WprojT[(size_t)(k0 + r0 + srow)*1024 + kc + sxor8];
      const ushort_t* srcB = &fBT[(size_t)(n0 + r0 + srow)*1024 + kc + sxor8];
      __builtin_amdgcn_global_load_lds((gvoid_t*)srcA, (lvoid_t*)&As[r0*64], 16, 0, 0);
      __builtin_amdgcn_global_load_lds((gvoid_t*)srcB, (lvoid_t*)&Bs[r0*64], 16, 0, 0);
    }
    __syncthreads();
    #pragma unroll
    for (int kk = 0; kk < 2; ++kk){
      int swz = (((kk*4 + lg) ^ (lr & 7)) * 8);
      short8 af = *reinterpret_cast<short8*>(&As[(wave*16 + lr)*64 + swz]);
      #pragma unroll
      for (int nf = 0; nf < 4; ++nf){
        short8 bf = *reinterpret_cast<short8*>(&Bs[(nf*16 + lr)*64 + swz]);
        acc[nf] = __builtin_amdgcn_mfma_f32_16x16x32_bf16(af, bf, acc[nf], 0, 0, 0);
      }
    }
  }
  // B-side ncol = n0 + nf*16 + lr -> n = nt*4 + nf, p = lr ; A-side k = k0 + wave*16 + lg*4 + r
  #pragma unroll
  for (int nf=0;nf<4;++nf){
    int ncol = n0 + nf*16 + lr;
    int nidx = ncol >> 4, p = ncol & 15;
    ushort4 ab;
    #pragma unroll
    for (int r=0;r<4;++r){
      int kh = k0 + wave*16 + lg*4 + r;
      float val = acc[nf][r] + b_proj[kh];
      A_flat[((size_t)nidx*1024 + kh)*16 + p] = val;
      (&ab.x)[r] = f2b(val);
      float s = val;
      s += __shfl_xor(s, 1, 64);
      s += __shfl_xor(s, 2, 64);
      s += __shfl_xor(s, 4, 64);
      s += __shfl_xor(s, 8, 64);
      if (lr == 0) hbuf[(nt*4 + nf)*1024 + kh] = s * (1.f/16.f);
    }
    *reinterpret_cast<ushort4*>(&Abt[(size_t)ncol*1024 + k0 + wave*16 + lg*4]) = ab;
  }
}

// ---------- P3[n][j][p] = sum_k Wattn[k][j] * A_flat[n][k][p]  (MFMA GEMM) ----------
__global__ void k_pmm(const ushort_t* __restrict__ WcatT, const ushort_t* __restrict__ Abt,
                      ushort_t* __restrict__ P3) {
  __shared__ ushort_t As[64*64];
  __shared__ ushort_t Bs[64*64];
  __shared__ ushort_t Dt2[64][72];
  int jt = blockIdx.x, nt = blockIdx.y;
  int j0 = jt*64, n0 = nt*64;
  int tid = threadIdx.x;
  int wave = tid>>6, lane = tid&63, lr = lane&15, lg = lane>>4;
  int srow = lane>>3, sxor8 = ((lane&7)^srow)*8;
  f32x4 acc[4];
  #pragma unroll
  for (int nf=0;nf<4;++nf) acc[nf] = (f32x4){0.f,0.f,0.f,0.f};
  for (int kc = 0; kc < 1024; kc += 64){
    __syncthreads();
    #pragma unroll
    for (int u = 0; u < 2; ++u){
      int r0 = wave*16 + u*8;
      const ushort_t* srcA = &WcatT[(size_t)(j0 + r0 + srow)*2560 + 1536 + kc + sxor8];
      const ushort_t* srcB = &Abt[(size_t)(n0 + r0 + srow)*1024 + kc + sxor8];
      __builtin_amdgcn_global_load_lds((gvoid_t*)srcA, (lvoid_t*)&As[r0*64], 16, 0, 0);
      __builtin_amdgcn_global_load_lds((gvoid_t*)srcB, (lvoid_t*)&Bs[r0*64], 16, 0, 0);
    }
    __syncthreads();
    #pragma unroll
    for (int kk = 0; kk < 2; ++kk){
      int swz = (((kk*4 + lg) ^ (lr & 7)) * 8);
      short8 af = *reinterpret_cast<short8*>(&As[(wave*16 + lr)*64 + swz]);
      #pragma unroll
      for (int nf = 0; nf < 4; ++nf){
        short8 bf = *reinterpret_cast<short8*>(&Bs[(nf*16 + lr)*64 + swz]);
        acc[nf] = __builtin_amdgcn_mfma_f32_16x16x32_bf16(af, bf, acc[nf], 0, 0, 0);
      }
    }
  }
  __syncthreads();
  #pragma unroll
  for (int nf=0;nf<4;++nf)
    #pragma unroll
    for (int r=0;r<4;++r)
      Dt2[wave*16 + lg*4 + r][nf*16 + lr] = f2b(acc[nf][r]);
  __syncthreads();
  // write P3[n][j][p]: ncol_local = seg*8 -> n_local = seg>>1, p0 = (seg&1)*8
  #pragma unroll
  for (int it=0; it<2; ++it){
    int e = it*256 + tid;          // 0..511
    int row = e >> 3, seg = e & 7;
    uint4 v = *reinterpret_cast<uint4*>(&Dt2[row][seg*8]);
    *reinterpret_cast<uint4*>(&P3[(((size_t)nt*4 + (seg>>1))*4096 + j0 + row)*16 + (seg&1)*8]) = v;
  }
}

// ---------- xpre[nt][j] = xb @ Wx ----------
__global__ void k_xmm(const ushort_t* __restrict__ WcatT, const ushort_t* __restrict__ xb,
                      ushort_t* __restrict__ xpre) {
  __shared__ ushort_t As[64*64];
  __shared__ ushort_t Bs[64*64];
  __shared__ float Dt[64][68];
  int jt = blockIdx.x, mt = blockIdx.y;
  int j0 = jt*64, m0 = mt*64;
  int tid = threadIdx.x;
  int wave = tid>>6, lane = tid&63, lr = lane&15, lg = lane>>4;
  int srow = lane>>3, sxor8 = ((lane&7)^srow)*8;
  f32x4 acc[4];
  #pragma unroll
  for (int nf=0;nf<4;++nf) acc[nf] = (f32x4){0.f,0.f,0.f,0.f};
  for (int kc = 0; kc < 512; kc += 64){
    __syncthreads();
    #pragma unroll
    for (int u = 0; u < 2; ++u){
      int r0 = wave*16 + u*8;
      const ushort_t* srcA = &WcatT[(size_t)(j0 + r0 + srow)*2560 + kc + sxor8];
      const ushort_t* srcB = &xb[(size_t)(m0 + r0 + srow)*512 + kc + sxor8];
      __builtin_amdgcn_global_load_lds((gvoid_t*)srcA, (lvoid_t*)&As[r0*64], 16, 0, 0);
      __builtin_amdgcn_global_load_lds((gvoid_t*)srcB, (lvoid_t*)&Bs[r0*64], 16, 0, 0);
    }
    __syncthreads();
    #pragma unroll
    for (int kk = 0; kk < 2; ++kk){
      int swz = (((kk*4 + lg) ^ (lr & 7)) * 8);
      short8 af = *reinterpret_cast<short8*>(&As[(wave*16 + lr)*64 + swz]);
      #pragma unroll
      for (int nf = 0; nf < 4; ++nf){
        short8 bf = *reinterpret_cast<short8*>(&Bs[(nf*16 + lr)*64 + swz]);
        acc[nf] = __builtin_amdgcn_mfma_f32_16x16x32_bf16(af, bf, acc[nf], 0, 0, 0);
      }
    }
  }
  __syncthreads();
  #pragma unroll
  for (int nf=0; nf<4; ++nf)
    #pragma unroll
    for (int r=0;r<4;++r)
      Dt[nf*16+lr][wave*16 + lg*4 + r] = acc[nf][r];
  __syncthreads();
  #pragma unroll
  for (int it=0; it<4; ++it){
    int e = tid + it*256;
    int nrow = e >> 4, seg = e & 15;
    float4 v = *reinterpret_cast<float4*>(&Dt[nrow][seg*4]);
    ushort4 o; o.x=f2b(v.x); o.y=f2b(v.y); o.z=f2b(v.z); o.w=f2b(v.w);
    *reinterpret_cast<ushort4*>(&xpre[(size_t)(m0+nrow)*4096 + j0 + seg*4]) = o;
  }
}

// ---------- per-step gates + c/h update + score partials (256 blocks) ----------
__global__ void k_gate(int i, const ushort_t* __restrict__ xpre, const float* __restrict__ a_part,
                       const float* __restrict__ bvec, const ushort_t* __restrict__ P3,
                       const float* __restrict__ A_flat, const float* __restrict__ hbuf,
                       float* __restrict__ cbuf, const float* __restrict__ sp_rd,
                       float* __restrict__ sp_wr, ushort_t* __restrict__ hbf,
                       ushort_t* __restrict__ hall) {
  __shared__ float wvLds[16];
  __shared__ float wred[4][16];
  int n = blockIdx.x >> 2, sp = blockIdx.x & 3;
  int tid = threadIdx.x;
  int wave = tid>>6, lane = tid&63;
  int k = sp*256 + tid;
  float hv;
  if (i == 0){
    hv = hbuf[n*1024 + k];
    cbuf[n*1024 + k] = hv;
    hbf[n*1024 + k] = f2b(hv);
  } else {
    if (tid < 16){
      float sv = (sp_rd[(n*4+0)*16+tid] + sp_rd[(n*4+1)*16+tid] +
                  sp_rd[(n*4+2)*16+tid] + sp_rd[(n*4+3)*16+tid]) * (1.f/32.f);
      float m = sv;
      #pragma unroll
      for (int d=1; d<16; d<<=1) m = fmaxf(m, __shfl_xor(m, d, 64));
      float e = __expf(sv - m);
      float s = e;
      #pragma unroll
      for (int d=1; d<16; d<<=1) s += __shfl_xor(s, d, 64);
      wvLds[tid] = e / s;
    }
    __syncthreads();
    float wv[16];
    #pragma unroll
    for (int p=0;p<16;++p) wv[p] = wvLds[p];
    float av[4];
    #pragma unroll
    for (int g=0;g<4;++g){
      int j = g*1024 + k;
      float x = bvec[j] + b2f(xpre[(size_t)(n*32 + (i-1))*4096 + j]);
      #pragma unroll
      for (int ks=0;ks<8;++ks) x += a_part[((size_t)ks*64 + n)*4096 + j];
      const ushort_t* pp = &P3[((size_t)n*4096 + j)*16];
      short8 p0 = *reinterpret_cast<const short8*>(pp);
      short8 p1 = *reinterpret_cast<const short8*>(pp+8);
      #pragma unroll
      for (int p=0;p<8;++p) x += wv[p]*b2f((ushort_t)p0[p]);
      #pragma unroll
      for (int p=0;p<8;++p) x += wv[8+p]*b2f((ushort_t)p1[p]);
      av[g]=x;
    }
    float ig=sigmoidf_(av[0]), fg=sigmoidf_(av[1]), og=sigmoidf_(av[2]), gg=tanhf(av[3]);
    float c = fg*cbuf[n*1024+k] + ig*gg;
    hv = og*tanhf(c);
    cbuf[n*1024+k] = c;
    hall[((size_t)n*32 + (i-1))*1024 + k] = f2b(hv);
    if (i < 32) hbf[n*1024+k] = f2b(hv);
  }
  if (i == 32) return;
  // score partials: spart[n][sp][p] = sum_{k in chunk} h[k] * A_flat[n][k][p]
  float sacc[16];
  const float* An = &A_flat[((size_t)n*1024 + k)*16];
  #pragma unroll
  for (int p=0;p<16;p+=4){
    float4 a4 = *reinterpret_cast<const float4*>(&An[p]);
    sacc[p] = hv*a4.x; sacc[p+1] = hv*a4.y; sacc[p+2] = hv*a4.z; sacc[p+3] = hv*a4.w;
  }
  #pragma unroll
  for (int d=1; d<64; d<<=1)
    #pragma unroll
    for (int p=0;p<16;++p) sacc[p] += __shfl_xor(sacc[p], d, 64);
  if (lane == 0)
    #pragma unroll
    for (int p=0;p<16;++p) wred[wave][p] = sacc[p];
  __syncthreads();
  if (tid < 16)
    sp_wr[(n*4+sp)*16 + tid] = wred[0][tid]+wred[1][tid]+wred[2][tid]+wred[3][tid];
}

// ---------- a_part[ks] = h @ Wh (K-chunk ks of 128; 512 blocks = 2/CU) ----------
__global__ void k_mm(const ushort_t* __restrict__ WcatT, const ushort_t* __restrict__ hbf,
                     float* __restrict__ a_part) {
  __shared__ ushort_t As[64*64];
  __shared__ ushort_t Bs[64*64];
  __shared__ float Dt[64][68];
  int jt = blockIdx.x, ks = blockIdx.y;
  int j0 = jt*64;
  int tid = threadIdx.x;
  int wave = tid>>6, lane = tid&63, lr = lane&15, lg = lane>>4;
  int srow = lane>>3, sxor8 = ((lane&7)^srow)*8;
  f32x4 acc[4];
  #pragma unroll
  for (int nf=0;nf<4;++nf) acc[nf] = (f32x4){0.f,0.f,0.f,0.f};
  for (int kc = 0; kc < 128; kc += 64){
    __syncthreads();
    #pragma unroll
    for (int u = 0; u < 2; ++u){
      int r0 = wave*16 + u*8;
      const ushort_t* srcA = &WcatT[(size_t)(j0 + r0 + srow)*2560 + 512 + ks*128 + kc + sxor8];
      const ushort_t* srcB = &hbf[(size_t)(r0 + srow)*1024 + ks*128 + kc + sxor8];
      __builtin_amdgcn_global_load_lds((gvoid_t*)srcA, (lvoid_t*)&As[r0*64], 16, 0, 0);
      __builtin_amdgcn_global_load_lds((gvoid_t*)srcB, (lvoid_t*)&Bs[r0*64], 16, 0, 0);
    }
    __syncthreads();
    #pragma unroll
    for (int kk = 0; kk < 2; ++kk){
      int swz = (((kk*4 + lg) ^ (lr & 7)) * 8);
      short8 af = *reinterpret_cast<short8*>(&As[(wave*16 + lr)*64 + swz]);
      #pragma unroll
      for (int nf = 0; nf < 4; ++nf){
        short8 bf = *reinterpret_cast<short8*>(&Bs[(nf*16 + lr)*64 + swz]);
        acc[nf] = __builtin_amdgcn_mfma_f32_16x16x32_bf16(af, bf, acc[nf], 0, 0, 0);
      }
    }
  }
  __syncthreads();
  #pragma unroll
  for (int nf=0; nf<4; ++nf)
    #pragma unroll
    for (int r=0;r<4;++r)
      Dt[nf*16+lr][wave*16 + lg*4 + r] = acc[nf][r];
  __syncthreads();
  #pragma unroll
  for (int it=0; it<4; ++it){
    int e = tid + it*256;
    int nrow = e >> 4, seg = e & 15;
    float4 v = *reinterpret_cast<float4*>(&Dt[nrow][seg*4]);
    *reinterpret_cast<float4*>(&a_part[((size_t)ks*64 + nrow)*4096 + j0 + seg*4]) = v;
  }
}

// ---------- scores tile + fused partial logsumexp over 128-v tile ----------
__global__ void __launch_bounds__(256, 4)
k_score(const ushort_t* __restrict__ WoutT, const ushort_t* __restrict__ hall,
        const float* __restrict__ b_out,
        float* __restrict__ pmax, float* __restrict__ psum) {
  __shared__ ushort_t As[128*64];
  __shared__ ushort_t Bs[128*64];
  __shared__ float bLds[128];
  __shared__ float pmLds[4][128];
  __shared__ float psLds[4][128];
  int bid = blockIdx.x;
  int wg = (bid & 7) * 500 + (bid >> 3);
  int vb = wg >> 4, rb = wg & 15;
  int v0 = vb * 128, r0 = rb * 128;
  int tid = threadIdx.x;
  int wave = tid >> 6, lane = tid & 63, lr = lane & 15, lg = lane >> 4;
  if (tid < 128) bLds[tid] = b_out[v0 + tid];

  int srow = lane >> 3;
  int sxor = ((lane & 7) ^ srow) << 3;

  f32x4 acc[2][8];
  #pragma unroll
  for (int a=0;a<2;++a)
    #pragma unroll
    for (int q=0;q<8;++q) acc[a][q]=(f32x4){0.f,0.f,0.f,0.f};

  for (int kc = 0; kc < 1024; kc += 64) {
    __syncthreads();
    #pragma unroll
    for (int i = 0; i < 4; ++i) {
      int rowg = (wave*4 + i) * 8;
      const ushort_t* gsA = &WoutT[(size_t)(v0 + rowg + srow)*1024 + kc + sxor];
      const ushort_t* gsB = &hall [(size_t)(r0 + rowg + srow)*1024 + kc + sxor];
      __builtin_amdgcn_global_load_lds((gvoid_t*)gsA, (lvoid_t*)&As[rowg*64], 16, 0, 0);
      __builtin_amdgcn_global_load_lds((gvoid_t*)gsB, (lvoid_t*)&Bs[rowg*64], 16, 0, 0);
    }
    __syncthreads();
    #pragma unroll
    for (int kk = 0; kk < 2; ++kk) {
      int swz = ((kk*4 + lg) ^ (lr & 7)) << 3;
      int rowA = wave*32 + lr;
      short8 af0 = *reinterpret_cast<short8*>(&As[rowA*64 + swz]);
      short8 af1 = *reinterpret_cast<short8*>(&As[(rowA+16)*64 + swz]);
      #pragma unroll
      for (int nr = 0; nr < 8; ++nr) {
        short8 bf = *reinterpret_cast<short8*>(&Bs[(nr*16+lr)*64 + swz]);
        acc[0][nr] = __builtin_amdgcn_mfma_f32_16x16x32_bf16(af0, bf, acc[0][nr], 0,0,0);
        acc[1][nr] = __builtin_amdgcn_mfma_f32_16x16x32_bf16(af1, bf, acc[1][nr], 0,0,0);
      }
    }
  }
  #pragma unroll
  for (int nr=0;nr<8;++nr){
    float m = -1e30f;
    float xv[8];
    #pragma unroll
    for (int mv=0;mv<2;++mv)
      #pragma unroll
      for (int r=0;r<4;++r){
        float x = acc[mv][nr][r] + bLds[wave*32 + mv*16 + lg*4 + r];
        xv[mv*4+r]=x; m = fmaxf(m,x);
      }
    float s=0.f;
    #pragma unroll
    for (int i=0;i<8;++i) s += __expf(xv[i]-m);
    #pragma unroll
    for (int d=16; d<=32; d<<=1){
      float om = __shfl_xor(m, d, 64);
      float os = __shfl_xor(s, d, 64);
      float nm = fmaxf(m, om);
      s = s*__expf(m-nm) + os*__expf(om-nm);
      m = nm;
    }
    if (lg == 0){
      pmLds[wave][nr*16+lr] = m;
      psLds[wave][nr*16+lr] = s;
    }
  }
  __syncthreads();
  if (tid < 128){
    float m=-1e30f;
    #pragma unroll
    for (int w=0;w<4;++w) m = fmaxf(m, pmLds[w][tid]);
    float s=0.f;
    #pragma unroll
    for (int w=0;w<4;++w) s += psLds[w][tid]*__expf(pmLds[w][tid]-m);
    pmax[(size_t)(r0+tid)*VTILES + vb] = m;
    psum[(size_t)(r0+tid)*VTILES + vb] = s;
  }
}

// ---------- target scores ----------
__global__ void k_tgt(const ushort_t* __restrict__ hall, const ushort_t* __restrict__ WoutT,
                      const float* __restrict__ b_out, const int* __restrict__ captions,
                      float* __restrict__ stgt) {
  int tid = threadIdx.x;
  int wave = tid>>6, lane = tid&63;
  int r = blockIdx.x*4 + wave;
  int n = r>>5, t = r&31;
  int y = captions[n*33 + t + 1];
  const ushort_t* hrow = hall + (size_t)r*1024;
  const ushort_t* wrow = WoutT + (size_t)y*1024;
  float dot = 0.f;
  #pragma unroll
  for (int i=0;i<2;++i){
    int off = lane*8 + i*512;
    short8 hv = *reinterpret_cast<const short8*>(&hrow[off]);
    short8 wv = *reinterpret_cast<const short8*>(&wrow[off]);
    #pragma unroll
    for (int e2=0;e2<8;++e2) dot += b2f((ushort_t)hv[e2])*b2f((ushort_t)wv[e2]);
  }
  #pragma unroll
  for (int d=32; d>=1; d>>=1) dot += __shfl_xor(dot, d, 64);
  if (lane==0) stgt[r] = dot + b_out[y];
}

// ---------- combine partials -> per-row masked nll ----------
__global__ void k_reduce(const float* __restrict__ pmax, const float* __restrict__ psum,
                         const float* __restrict__ stgt, const int* __restrict__ captions,
                         float* __restrict__ row_loss) {
  int tid = threadIdx.x;
  int wave = tid>>6, lane = tid&63;
  int r = blockIdx.x*4 + wave;
  float m = -1e30f, s = 0.f;
  for (int j = lane; j < VTILES; j += 64){
    float mj = pmax[(size_t)r*VTILES + j];
    float sj = psum[(size_t)r*VTILES + j];
    float nm = fmaxf(m, mj);
    s = s*__expf(m-nm) + sj*__expf(mj-nm);
    m = nm;
  }
  #pragma unroll
  for (int d=32; d>=1; d>>=1){
    float om = __shfl_xor(m, d, 64);
    float os = __shfl_xor(s, d, 64);
    float nm = fmaxf(m, om);
    s = s*__expf(m-nm) + os*__expf(om-nm);
    m = nm;
  }
  if (lane==0){
    int n = r>>5, t = r&31;
    int y = captions[n*33 + t + 1];
    float lse = m + __logf(s);
    row_loss[r] = (y != 0) ? (lse - stgt[r]) : 0.f;
  }
}

// ---------- final deterministic sum ----------
__global__ void k_final(const float* __restrict__ row_loss, float* __restrict__ out) {
  __shared__ float red[256];
  int tid = threadIdx.x;
  float s = 0.f;
  #pragma unroll
  for (int i=0;i<8;++i) s += row_loss[tid + i*256];
  red[tid] = s;
  __syncthreads();
  for (int off=128; off>=1; off>>=1){
    if (tid<off) red[tid] += red[tid+off];
    __syncthreads();
  }
  if (tid==0) out[0] = red[0] * (1.f/64.f);
}

extern "C" void kernel_launch(void* const* d_in, const int* in_sizes, int n_in,
                              void* d_out, int out_size, void* d_ws, size_t ws_size,
                              hipStream_t stream) {
  const float* features = (const float*)d_in[0];
  const int*   captions = (const int*)d_in[1];
  const float* W_embed  = (const float*)d_in[2];
  const float* Wx       = (const float*)d_in[3];
  const float* Wh       = (const float*)d_in[4];
  const float* Wattn    = (const float*)d_in[5];
  const float* b        = (const float*)d_in[6];
  const float* W_proj   = (const float*)d_in[7];
  const float* b_proj   = (const float*)d_in[8];
  const float* W_out    = (const float*)d_in[9];
  const float* b_out    = (const float*)d_in[10];
  float* out = (float*)d_out;

  char* wsp = (char*)d_ws;
  size_t off = 0;
  auto alloc = [&](size_t bytes)->char*{
    char* p = wsp + off; off += (bytes + 255) & ~(size_t)255; return p;
  };
  ushort_t* WcatT  = (ushort_t*)alloc((size_t)4096*2560*2);
  ushort_t* WoutT  = (ushort_t*)alloc((size_t)32000*1024*2);
  ushort_t* WprojT = (ushort_t*)alloc((size_t)1024*1024*2);
  ushort_t* fBT    = (ushort_t*)alloc((size_t)1024*1024*2);
  ushort_t* Abt    = (ushort_t*)alloc((size_t)1024*1024*2);
  float* A_flat    = (float*)alloc((size_t)64*1024*16*4);
  ushort_t* xb     = (ushort_t*)alloc((size_t)64*32*512*2);
  float* hbuf      = (float*)alloc((size_t)64*1024*4);
  ushort_t* P3     = (ushort_t*)alloc((size_t)64*4096*16*2);
  ushort_t* xpre   = (ushort_t*)alloc((size_t)2048*4096*2);
  float* a_part    = (float*)alloc((size_t)8*64*4096*4);
  ushort_t* hbf    = (ushort_t*)alloc((size_t)64*1024*2);
  float* cbuf      = (float*)alloc((size_t)64*1024*4);
  float* spbuf     = (float*)alloc((size_t)2*64*4*16*4);
  ushort_t* hall   = (ushort_t*)alloc((size_t)2048*1024*2);
  float* pmax      = (float*)alloc((size_t)2048*250*4);
  float* psum      = (float*)alloc((size_t)2048*250*4);
  float* stgt      = (float*)alloc((size_t)2048*4);
  float* row_loss  = (float*)alloc((size_t)2048*4);

  hipLaunchKernelGGL(k_transpose_cvt, dim3(64, 8),   dim3(256), 0, stream, Wx,     WcatT,  4096, 2560, 0);
  hipLaunchKernelGGL(k_transpose_cvt, dim3(64, 16),  dim3(256), 0, stream, Wh,     WcatT,  4096, 2560, 512);
  hipLaunchKernelGGL(k_transpose_cvt, dim3(64, 16),  dim3(256), 0, stream, Wattn,  WcatT,  4096, 2560, 1536);
  hipLaunchKernelGGL(k_transpose_cvt, dim3(500, 16), dim3(256), 0, stream, W_out,  WoutT,  32000, 1024, 0);
  hipLaunchKernelGGL(k_transpose_cvt, dim3(16, 16),  dim3(256), 0, stream, W_proj, WprojT, 1024, 1024, 0);
  hipLaunchKernelGGL(k_featT, dim3(64), dim3(256), 0, stream, features, fBT);
  hipLaunchKernelGGL(k_embed, dim3(1024), dim3(256), 0, stream, captions, W_embed, xb);
  hipLaunchKernelGGL(k_projmm, dim3(16, 16), dim3(256), 0, stream, WprojT, fBT, b_proj, A_flat, Abt, hbuf);
  hipLaunchKernelGGL(k_pmm, dim3(64, 16), dim3(256), 0, stream, WcatT, Abt, P3);
  hipLaunchKernelGGL(k_xmm, dim3(64, 32), dim3(256), 0, stream, WcatT, xb, xpre);

  for (int i = 0; i <= 32; ++i){
    const float* sp_rd = spbuf + ((i+1)&1)*4096;
    float*       sp_wr = spbuf + (i&1)*4096;
    hipLaunchKernelGGL(k_gate, dim3(256), dim3(256), 0, stream, i, xpre, a_part, b, P3,
                       A_flat, hbuf, cbuf, sp_rd, sp_wr, hbf, hall);
    if (i < 32)
      hipLaunchKernelGGL(k_mm, dim3(64, 8), dim3(256), 0, stream, WcatT, hbf, a_part);
  }

  hipLaunchKernelGGL(k_score, dim3(4000), dim3(256), 0, stream, WoutT, hall, b_out, pmax, psum);
  hipLaunchKernelGGL(k_tgt, dim3(512), dim3(256), 0, stream, hall, WoutT, b_out, captions, stgt);
  hipLaunchKernelGGL(k_reduce, dim3(512), dim3(256), 0, stream, pmax, psum, stgt, captions, row_loss);
  hipLaunchKernelGGL(k_final, dim3(1), dim3(256), 0, stream, row_loss, out);
}